// Round 10
// baseline (2113.785 us; speedup 1.0000x reference)
//
#include <hip/hip_runtime.h>

// ---------------------------------------------------------------------------
// AttentionDecoder: B=64 T=32 S=64 H=1024 V=32000
// R10: R7/R9 skeleton + phase-latency attack.
//  - gh-GEMM moved into the Ph3 slot (runs concurrently with l2b GEMM on
//    disjoint blocks; gh(t+1) needs only hh_r[t+1], ready since bar2(t)).
//    Ph1 slot = gi only. Serial GEMM time per step shrinks ~2.5us.
//  - 2-deep register prefetch (pa/pb tile sets) in all GEMM kt loops.
//  - Barrier split into arrive/wait; between them blocks pre-warm the next
//    phase's already-legal inputs (embi before bar1; hh A-tiles before bar3).
//  - gi/gh epilogues: shfl-pack adjacent cols -> u64 atomic stores (halves
//    coherent-point store ops).
//  - Coherence protocol (atomic producers / rotation-fresh cached consumers),
//    quarter-sliced Ph2a/2c, LDS-resident weights: unchanged from R7/R9.
// ---------------------------------------------------------------------------

#define B_ 64
#define T_ 32
#define S_ 64
#define H_ 1024
#define V_ 32000
#define NB_ 256
#define LDS_BYTES 152064
// LDS: [0,65536) W_HI | [65536,131072) W_LO | [131072,147456) A_HI/A_LO
//      [147456,148480) hq f32[256] | [148480,148736) at_s f32[64]
//      Ph3 reuses [131072,139264) as f32 C-tile

#define HID_OFF 65536000L
#define ATT_OFF 65601536L
#define CTF_OFF 65732608L

typedef __attribute__((ext_vector_type(8))) short bf16x8;
typedef __attribute__((ext_vector_type(4))) float f32x4;
typedef __attribute__((ext_vector_type(4))) unsigned int u32x4;
typedef unsigned short u16;
typedef unsigned long long u64;

__device__ __forceinline__ u16 f2bf(float v) {
  unsigned int u = __float_as_uint(v);
  unsigned int r = (u + 0x7fffu + ((u >> 16) & 1u)) >> 16;  // RNE
  return (u16)r;
}
__device__ __forceinline__ float bf2f(u16 h) {
  return __uint_as_float(((unsigned int)h) << 16);
}
__device__ __forceinline__ void split2(float v, u16* hi, u16* lo) {
  u16 h = f2bf(v);
  *hi = h;
  *lo = f2bf(v - bf2f(h));
}

// ---- coherent-path (agent-scope relaxed atomic) helpers ----
__device__ __forceinline__ u64 aload_u64(const void* p) {
  return __hip_atomic_load((const u64*)p, __ATOMIC_RELAXED, __HIP_MEMORY_SCOPE_AGENT);
}
__device__ __forceinline__ unsigned aload_u32(const void* p) {
  return __hip_atomic_load((const unsigned*)p, __ATOMIC_RELAXED, __HIP_MEMORY_SCOPE_AGENT);
}
__device__ __forceinline__ void astore_u64(void* p, u64 v) {
  __hip_atomic_store((u64*)p, v, __ATOMIC_RELAXED, __HIP_MEMORY_SCOPE_AGENT);
}
__device__ __forceinline__ void astore_f32(float* p, float v) {
  __hip_atomic_store((unsigned*)p, __float_as_uint(v), __ATOMIC_RELAXED,
                     __HIP_MEMORY_SCOPE_AGENT);
}

// ---------------- conversion / prep kernels ----------------

__global__ void k_split(const float* __restrict__ src, u16* __restrict__ hi,
                        u16* __restrict__ lo, int n) {
  int i = blockIdx.x * blockDim.x + threadIdx.x;
  int stride = gridDim.x * blockDim.x;
  for (; i < n; i += stride) split2(src[i], &hi[i], &lo[i]);
}

__global__ void k_tobf(const float* __restrict__ src, u16* __restrict__ dst, int n) {
  int i = blockIdx.x * blockDim.x + threadIdx.x;
  int stride = gridDim.x * blockDim.x;
  for (; i < n; i += stride) dst[i] = f2bf(src[i]);
}

// l1 (H,H) row-major [i][k] -> l1T hi/lo [k][i]
__global__ void k_l1t(const float* __restrict__ l1, u16* __restrict__ hi,
                      u16* __restrict__ lo) {
  __shared__ float tile[64][65];
  int it = blockIdx.x & 15, kt = blockIdx.x >> 4;
  for (int q = 0; q < 16; ++q) {
    int idx = q * 256 + threadIdx.x;
    int r = idx >> 6, c = idx & 63;
    tile[r][c] = l1[(long)(it * 64 + r) * H_ + kt * 64 + c];
  }
  __syncthreads();
  for (int q = 0; q < 16; ++q) {
    int idx = q * 256 + threadIdx.x;
    int r = idx >> 6, c = idx & 63;
    long o = (long)(kt * 64 + r) * H_ + it * 64 + c;
    split2(tile[c][r], &hi[o], &lo[o]);
  }
}

// gather embeddings: embx[t][b][k] hi/lo
__global__ void k_embx(const int* __restrict__ inp, const float* __restrict__ emb,
                       u16* __restrict__ hi, u16* __restrict__ lo) {
  int bt = blockIdx.x;
  int b = bt >> 5, t = bt & 31;
  int id = inp[b * T_ + t];
  const float* src = emb + (long)id * H_;
  long base = (long)(t * B_ + b) * H_;
  for (int k = threadIdx.x; k < H_; k += 256) split2(src[k], &hi[base + k], &lo[base + k]);
}

// h0 -> hh_r/hl_r slot 0
__global__ void k_h0(const float* __restrict__ mem, u16* __restrict__ hh,
                     u16* __restrict__ hl) {
  int i = blockIdx.x * 256 + threadIdx.x;  // 65536
  float v = mem[i];
  split2(v, &hh[i], &hl[i]);
}

__global__ void k_guard(float* out, float v) {
  if (blockIdx.x == 0 && threadIdx.x == 0) out[0] = v;
}

// ---------------- 128x128 tile GEMM (BK=32), optional split-bf16 ----------------
template <int SPLIT, int OMODE>
__launch_bounds__(256)
__global__ void k_gemm128(const u16* __restrict__ Ah, const u16* __restrict__ Al,
                          const u16* __restrict__ Bh, const u16* __restrict__ Bl,
                          float* __restrict__ C, const float* __restrict__ bias,
                          int Mtiles, int Ntiles, int K, int Arow, int Brow, int Crow) {
  (void)Ntiles;
  int bx = blockIdx.x;
  int mt = bx % Mtiles, nt = bx / Mtiles;
  int m0 = mt * 128, n0 = nt * 128;

  __shared__ __attribute__((aligned(16))) u16 lds[(SPLIT ? 4 : 2) * 4096];
  char* L = (char*)lds;
  const int tid = threadIdx.x;
  const int lane = tid & 63, wid = tid >> 6;
  const int wm = wid & 1, wn = wid >> 1;
  const int l15 = lane & 15, kq = lane >> 4;

  f32x4 acc[4][4];
  const f32x4 z4 = {0.f, 0.f, 0.f, 0.f};
#pragma unroll
  for (int i = 0; i < 4; ++i)
#pragma unroll
    for (int j = 0; j < 4; ++j) acc[i][j] = z4;

  const int ksteps = K >> 5;
  for (int kt = 0; kt < ksteps; ++kt) {
    __syncthreads();
#pragma unroll
    for (int h2 = 0; h2 < 2; ++h2) {
      int r = (tid >> 2) + (h2 << 6);
      int slot = tid & 3;
      int so = ((slot ^ (r & 3)) << 4);
      long ga = (long)(m0 + r) * Arow + (kt << 5) + (slot << 3);
      long gb = (long)(n0 + r) * Brow + (kt << 5) + (slot << 3);
      *(u32x4*)(L + r * 64 + so) = *(const u32x4*)(Ah + ga);
      *(u32x4*)(L + 8192 + r * 64 + so) = *(const u32x4*)(Bh + gb);
      if (SPLIT) {
        *(u32x4*)(L + 16384 + r * 64 + so) = *(const u32x4*)(Al + ga);
        *(u32x4*)(L + 24576 + r * 64 + so) = *(const u32x4*)(Bl + gb);
      }
    }
    __syncthreads();
    bf16x8 aH[4], bH[4], aL[4], bL[4];
#pragma unroll
    for (int mi = 0; mi < 4; ++mi) {
      int r = (wm << 6) + (mi << 4) + l15;
      int off = r * 64 + ((kq ^ (r & 3)) << 4);
      aH[mi] = *(const bf16x8*)(L + off);
      if (SPLIT) aL[mi] = *(const bf16x8*)(L + 16384 + off);
    }
#pragma unroll
    for (int ni = 0; ni < 4; ++ni) {
      int c = (wn << 6) + (ni << 4) + l15;
      int off = c * 64 + ((kq ^ (c & 3)) << 4);
      bH[ni] = *(const bf16x8*)(L + 8192 + off);
      if (SPLIT) bL[ni] = *(const bf16x8*)(L + 24576 + off);
    }
#pragma unroll
    for (int mi = 0; mi < 4; ++mi)
#pragma unroll
      for (int ni = 0; ni < 4; ++ni) {
        acc[mi][ni] = __builtin_amdgcn_mfma_f32_16x16x32_bf16(aH[mi], bH[ni], acc[mi][ni], 0, 0, 0);
        if (SPLIT) {
          acc[mi][ni] = __builtin_amdgcn_mfma_f32_16x16x32_bf16(aL[mi], bH[ni], acc[mi][ni], 0, 0, 0);
          acc[mi][ni] = __builtin_amdgcn_mfma_f32_16x16x32_bf16(aH[mi], bL[ni], acc[mi][ni], 0, 0, 0);
        }
      }
  }
#pragma unroll
  for (int mi = 0; mi < 4; ++mi)
#pragma unroll
    for (int ni = 0; ni < 4; ++ni)
#pragma unroll
      for (int e = 0; e < 4; ++e) {
        int r = (wm << 6) + (mi << 4) + (kq << 2) + e;
        int c = (wn << 6) + (ni << 4) + l15;
        int gm = m0 + r, gn = n0 + c;
        float v = acc[mi][ni][e];
        if (OMODE == 0) {
          C[(long)gm * Crow + gn] = v;
        } else {
          v += bias[gn];
          C[((long)(gm & 63) * T_ + (gm >> 6)) * V_ + gn] = v;
        }
      }
}

// ---------------- 2-level counter barrier (arrive / wait split) ----------------
// flags[g*64]: 8 group counters (32 blocks each) | flags[1024]: root | flags[1040]: gen
__device__ __forceinline__ void gb_arrive(unsigned* flags, unsigned seq) {
  __syncthreads();
  if (threadIdx.x == 0) {
    unsigned g = blockIdx.x & 7u;
    unsigned old = __hip_atomic_fetch_add(flags + g * 64, 1u, __ATOMIC_RELEASE,
                                          __HIP_MEMORY_SCOPE_AGENT);
    if (old == seq * 32u - 1u) {
      unsigned o2 = __hip_atomic_fetch_add(flags + 1024, 1u, __ATOMIC_RELEASE,
                                           __HIP_MEMORY_SCOPE_AGENT);
      if (o2 == seq * 8u - 1u)
        __hip_atomic_store(flags + 1040, seq, __ATOMIC_RELAXED,
                           __HIP_MEMORY_SCOPE_AGENT);
    }
  }
}
__device__ __forceinline__ void gb_wait(unsigned* flags, unsigned seq) {
  if (threadIdx.x == 0) {
    while (__hip_atomic_load(flags + 1040, __ATOMIC_RELAXED,
                             __HIP_MEMORY_SCOPE_AGENT) < seq)
      __builtin_amdgcn_s_sleep(2);
  }
  __syncthreads();
}
__device__ __forceinline__ void gridbar(unsigned* flags, unsigned seq) {
  gb_arrive(flags, seq);
  gb_wait(flags, seq);
}

// ---------------- 64-row GEMM slab vs LDS-resident W, 2-deep A prefetch ------
// NI=2: 64-col output (gi/gh); NI=1: 32-col (l2b). NKT k-tiles of 64.
template <int NI, int NKT>
__device__ __forceinline__ void gemm_slab(const u16* __restrict__ Ah,
                                          const u16* __restrict__ Al,
                                          char* W_HI, char* W_LO, char* A_HI,
                                          char* A_LO, int wm, int wn, int l15,
                                          int kq, int pr, int ps, int ao,
                                          f32x4 (&acc)[2][NI]) {
  const int wsub = (NI == 2) ? 4096 : 2048;
  const long g0 = (long)pr * 1024 + ps * 8;
  u32x4 pa0, pa1, pa2, pa3, pb0, pb1, pb2, pb3;
  {
    pa0 = *(const u32x4*)(Ah + g0);      pa1 = *(const u32x4*)(Ah + g0 + 32);
    pa2 = *(const u32x4*)(Al + g0);      pa3 = *(const u32x4*)(Al + g0 + 32);
    pb0 = *(const u32x4*)(Ah + g0 + 64); pb1 = *(const u32x4*)(Ah + g0 + 96);
    pb2 = *(const u32x4*)(Al + g0 + 64); pb3 = *(const u32x4*)(Al + g0 + 96);
  }
#pragma unroll
  for (int kt = 0; kt < NKT; kt += 2) {
    // ---- even kt: stage pa, prefetch kt+2 ----
    __syncthreads();
    *(u32x4*)(A_HI + ao) = pa0; *(u32x4*)(A_HI + 4096 + ao) = pa1;
    *(u32x4*)(A_LO + ao) = pa2; *(u32x4*)(A_LO + 4096 + ao) = pa3;
    __syncthreads();
    if (kt + 2 < NKT) {
      long g = g0 + (long)(kt + 2) * 64;
      pa0 = *(const u32x4*)(Ah + g);      pa1 = *(const u32x4*)(Ah + g + 32);
      pa2 = *(const u32x4*)(Al + g);      pa3 = *(const u32x4*)(Al + g + 32);
    }
#pragma unroll
    for (int sub = 0; sub < 2; ++sub) {
      const int stw = (kt * 2 + sub) * wsub;
      const int sta = sub * 4096;
      bf16x8 aH[2], aL[2], bH[NI], bL[NI];
#pragma unroll
      for (int mi = 0; mi < 2; ++mi) {
        int rr = (wm << 5) + (mi << 4) + l15;
        int off = rr * 64 + ((kq ^ (rr & 3)) << 4);
        aH[mi] = *(const bf16x8*)(A_HI + sta + off);
        aL[mi] = *(const bf16x8*)(A_LO + sta + off);
      }
#pragma unroll
      for (int ni = 0; ni < NI; ++ni) {
        int c = (wn << (NI == 2 ? 5 : 4)) + (ni << 4) + l15;
        int off = c * 64 + ((kq ^ (c & 3)) << 4);
        bH[ni] = *(const bf16x8*)(W_HI + stw + off);
        bL[ni] = *(const bf16x8*)(W_LO + stw + off);
      }
#pragma unroll
      for (int mi = 0; mi < 2; ++mi)
#pragma unroll
        for (int ni = 0; ni < NI; ++ni) {
          acc[mi][ni] = __builtin_amdgcn_mfma_f32_16x16x32_bf16(aH[mi], bH[ni], acc[mi][ni], 0, 0, 0);
          acc[mi][ni] = __builtin_amdgcn_mfma_f32_16x16x32_bf16(aL[mi], bH[ni], acc[mi][ni], 0, 0, 0);
          acc[mi][ni] = __builtin_amdgcn_mfma_f32_16x16x32_bf16(aH[mi], bL[ni], acc[mi][ni], 0, 0, 0);
        }
    }
    // ---- odd kt: stage pb, prefetch kt+3 ----
    __syncthreads();
    *(u32x4*)(A_HI + ao) = pb0; *(u32x4*)(A_HI + 4096 + ao) = pb1;
    *(u32x4*)(A_LO + ao) = pb2; *(u32x4*)(A_LO + 4096 + ao) = pb3;
    __syncthreads();
    if (kt + 3 < NKT) {
      long g = g0 + (long)(kt + 3) * 64;
      pb0 = *(const u32x4*)(Ah + g);      pb1 = *(const u32x4*)(Ah + g + 32);
      pb2 = *(const u32x4*)(Al + g);      pb3 = *(const u32x4*)(Al + g + 32);
    }
#pragma unroll
    for (int sub = 0; sub < 2; ++sub) {
      const int stw = ((kt + 1) * 2 + sub) * wsub;
      const int sta = sub * 4096;
      bf16x8 aH[2], aL[2], bH[NI], bL[NI];
#pragma unroll
      for (int mi = 0; mi < 2; ++mi) {
        int rr = (wm << 5) + (mi << 4) + l15;
        int off = rr * 64 + ((kq ^ (rr & 3)) << 4);
        aH[mi] = *(const bf16x8*)(A_HI + sta + off);
        aL[mi] = *(const bf16x8*)(A_LO + sta + off);
      }
#pragma unroll
      for (int ni = 0; ni < NI; ++ni) {
        int c = (wn << (NI == 2 ? 5 : 4)) + (ni << 4) + l15;
        int off = c * 64 + ((kq ^ (c & 3)) << 4);
        bH[ni] = *(const bf16x8*)(W_HI + stw + off);
        bL[ni] = *(const bf16x8*)(W_LO + stw + off);
      }
#pragma unroll
      for (int mi = 0; mi < 2; ++mi)
#pragma unroll
        for (int ni = 0; ni < NI; ++ni) {
          acc[mi][ni] = __builtin_amdgcn_mfma_f32_16x16x32_bf16(aH[mi], bH[ni], acc[mi][ni], 0, 0, 0);
          acc[mi][ni] = __builtin_amdgcn_mfma_f32_16x16x32_bf16(aL[mi], bH[ni], acc[mi][ni], 0, 0, 0);
          acc[mi][ni] = __builtin_amdgcn_mfma_f32_16x16x32_bf16(aH[mi], bL[ni], acc[mi][ni], 0, 0, 0);
        }
    }
  }
}

// gi/gh epilogue: shfl-pack adjacent cols, u64 stores from even-l15 lanes
__device__ __forceinline__ void epi_pack(float* __restrict__ outp,
                                         f32x4 (&acc)[2][2], int wm, int wn,
                                         int l15, int kq) {
#pragma unroll
  for (int mi = 0; mi < 2; ++mi)
#pragma unroll
    for (int ni = 0; ni < 2; ++ni)
#pragma unroll
      for (int e = 0; e < 4; ++e) {
        int r = (wm << 5) + (mi << 4) + (kq << 2) + e;
        int c = (wn << 5) + (ni << 4) + l15;
        float v = acc[mi][ni][e];
        float o = __shfl_xor(v, 1);
        if (!(l15 & 1)) {
          u64 pk = ((u64)__float_as_uint(o) << 32) | __float_as_uint(v);
          astore_u64(outp + (long)r * 3072 + c, pk);
        }
      }
}

// ---------------- persistent recurrence kernel ----------------
__launch_bounds__(256)
__global__ void k_rec(const float* __restrict__ embi,
                      u16* __restrict__ dctx_h, u16* __restrict__ dctx_l,
                      u16* __restrict__ hh_r, u16* __restrict__ hl_r,
                      const float* __restrict__ memory,
                      const u16* __restrict__ wih_h, const u16* __restrict__ wih_l,
                      const u16* __restrict__ whh_h, const u16* __restrict__ whh_l,
                      const u16* __restrict__ l2_h, const u16* __restrict__ l2_l,
                      float* __restrict__ gip, float* __restrict__ ghp,
                      float* __restrict__ psc, float* __restrict__ ctxp,
                      const float* __restrict__ encT, const float* __restrict__ encL,
                      const int* __restrict__ xs_len,
                      const float* __restrict__ bih, const float* __restrict__ bhh,
                      float* __restrict__ dout, unsigned* flags) {
  extern __shared__ __attribute__((aligned(16))) char L[];
  char* W_HI = L;
  char* W_LO = L + 65536;
  char* A_HI = L + 131072;
  char* A_LO = L + 139264;
  float* hq = (float*)(L + 147456);
  float* at_s = (float*)(L + 148480);
  const int bx = blockIdx.x;
  const int tid = threadIdx.x;
  const int lane = tid & 63, wid = tid >> 6;
  const int wm = wid & 1, wn = wid >> 1;
  const int l15 = lane & 15, kq = lane >> 4;
  const f32x4 z4 = {0.f, 0.f, 0.f, 0.f};
  unsigned seq = 1;

  // ---- role decode ----
  const int isGI = (bx < 96);
  const int isGH = (bx >= 96 && bx < 192);
  const int isL2 = (bx >= 192 && bx < 224);
  const int sb = bx >> 2;        // Ph2 batch
  const int sq = bx & 3;         // Ph2 quarter
  int nt = 0, kc = 0, n0 = 0;
  const u16 *Wg_h = nullptr, *Wg_l = nullptr;
  int wrs = 0;
  if (isGI) {
    nt = bx % 48; kc = bx / 48;
    Wg_h = wih_h + 1024 + (long)nt * 64 * 2048 + kc * 512;
    Wg_l = wih_l + 1024 + (long)nt * 64 * 2048 + kc * 512;
    wrs = 2048;
  } else if (isGH) {
    int j2 = bx - 96;
    nt = j2 % 48; kc = j2 / 48;
    Wg_h = whh_h + (long)nt * 64 * 1024 + kc * 512;
    Wg_l = whh_l + (long)nt * 64 * 1024 + kc * 512;
    wrs = 1024;
  } else if (isL2) {
    n0 = (bx - 192) << 5;
    Wg_h = l2_h + 1024 + (long)n0 * 2048;
    Wg_l = l2_l + 1024 + (long)n0 * 2048;
    wrs = 2048;
  }

  // ---- one-time: load weight slab into LDS ----
  if (isGI || isGH) {
    for (int e = tid; e < 4096; e += 256) {
      int st = e >> 8, r = (e >> 2) & 63, slot = e & 3;
      long g = (long)r * wrs + st * 32 + slot * 8;
      int o = st * 4096 + r * 64 + ((slot ^ (r & 3)) << 4);
      *(u32x4*)(W_HI + o) = *(const u32x4*)(Wg_h + g);
      *(u32x4*)(W_LO + o) = *(const u32x4*)(Wg_l + g);
    }
  } else if (isL2) {
    for (int e = tid; e < 4096; e += 256) {
      int st = e >> 7, r = (e >> 2) & 31, slot = e & 3;
      long g = (long)r * wrs + st * 32 + slot * 8;
      int o = st * 2048 + r * 64 + ((slot ^ (r & 3)) << 4);
      *(u32x4*)(W_HI + o) = *(const u32x4*)(Wg_h + g);
      *(u32x4*)(W_LO + o) = *(const u32x4*)(Wg_l + g);
    }
  }
  __syncthreads();

  // h_prev element owned by this thread: h[sb][sq*256 + tid]
  float hpv = memory[sb * 1024 + sq * 256 + tid];

  // A-staging thread constants
  const int pr = tid >> 2, ps = tid & 3;
  const int ao = pr * 64 + ((ps ^ (pr & 3)) << 4);
  const long g0w = (long)pr * 1024 + ps * 8;

  for (int t = 0; t < T_; ++t) {
    // ============ Ph1 slot: gi(t) always; gh(0) only at t==0 ============
    if (isGI) {
      f32x4 acc[2][2];
#pragma unroll
      for (int i = 0; i < 2; ++i)
#pragma unroll
        for (int j = 0; j < 2; ++j) acc[i][j] = z4;
      gemm_slab<2, 8>(dctx_h + (long)t * 65536 + kc * 512,
                      dctx_l + (long)t * 65536 + kc * 512,
                      W_HI, W_LO, A_HI, A_LO, wm, wn, l15, kq, pr, ps, ao, acc);
      epi_pack(gip + (long)kc * 196608 + nt * 64, acc, wm, wn, l15, kq);
    } else if (isGH && t == 0) {
      f32x4 acc[2][2];
#pragma unroll
      for (int i = 0; i < 2; ++i)
#pragma unroll
        for (int j = 0; j < 2; ++j) acc[i][j] = z4;
      gemm_slab<2, 8>(hh_r + kc * 512, hl_r + kc * 512,
                      W_HI, W_LO, A_HI, A_LO, wm, wn, l15, kq, pr, ps, ao, acc);
      epi_pack(ghp + (long)kc * 196608 + nt * 64, acc, wm, wn, l15, kq);
    }
    // bar1: pre-warm embi (always legal) between arrive and wait
    gb_arrive(flags, seq);
    {
      const float* eb = embi + ((long)t * 64 + sb) * 3072;
      int j = (sq << 8) + tid;
      float w0 = eb[j], w1 = eb[1024 + j], w2 = eb[2048 + j];
      asm volatile("" :: "v"(w0), "v"(w1), "v"(w2));
    }
    gb_wait(flags, seq); seq++;

    // ========== Ph2a: GRU quarter + partial scores (ALL 256 blocks) ========
    {
      const int b = sb, q = sq;
      const int j = (q << 8) + tid;
      const float* eb = embi + ((long)t * 64 + b) * 3072;
      float g0r = __uint_as_float(aload_u32(gip + b * 3072 + j));
      float g1r = __uint_as_float(aload_u32(gip + 196608 + b * 3072 + j));
      float g0z = __uint_as_float(aload_u32(gip + b * 3072 + 1024 + j));
      float g1z = __uint_as_float(aload_u32(gip + 196608 + b * 3072 + 1024 + j));
      float g0n = __uint_as_float(aload_u32(gip + b * 3072 + 2048 + j));
      float g1n = __uint_as_float(aload_u32(gip + 196608 + b * 3072 + 2048 + j));
      float h0r = __uint_as_float(aload_u32(ghp + b * 3072 + j));
      float h1r = __uint_as_float(aload_u32(ghp + 196608 + b * 3072 + j));
      float h0z = __uint_as_float(aload_u32(ghp + b * 3072 + 1024 + j));
      float h1z = __uint_as_float(aload_u32(ghp + 196608 + b * 3072 + 1024 + j));
      float h0n = __uint_as_float(aload_u32(ghp + b * 3072 + 2048 + j));
      float h1n = __uint_as_float(aload_u32(ghp + 196608 + b * 3072 + 2048 + j));
      float ir = eb[j] + g0r + g1r + bih[j];
      float iz = eb[1024 + j] + g0z + g1z + bih[1024 + j];
      float in2 = eb[2048 + j] + g0n + g1n + bih[2048 + j];
      float hr = h0r + h1r + bhh[j];
      float hz = h0z + h1z + bhh[1024 + j];
      float hn = h0n + h1n + bhh[2048 + j];
      float r = 1.f / (1.f + expf(-(ir + hr)));
      float z = 1.f / (1.f + expf(-(iz + hz)));
      float n = tanhf(in2 + r * hn);
      float h = (1.f - z) * n + z * hpv;
      hpv = h;
      hq[tid] = h;
      if (t == T_ - 1) dout[HID_OFF + (long)b * 1024 + j] = h;
      __syncthreads();
      // pack h quarter -> bf16 hi/lo rotated slot (wave 0)
      if (tid < 64) {
        u64 ph = 0, pl = 0;
#pragma unroll
        for (int ii = 0; ii < 4; ++ii) {
          u16 hi, lo;
          split2(hq[tid * 4 + ii], &hi, &lo);
          ph |= (u64)hi << (16 * ii);
          pl |= (u64)lo << (16 * ii);
        }
        long o = (long)(t + 1) * 65536 + (long)b * 1024 + (q << 8) + tid * 4;
        astore_u64(hh_r + o, ph);
        astore_u64(hl_r + o, pl);
      }
      // partial scores: 4 threads per s over 64-k sub-slices (f32 encT)
      {
        int s = tid >> 2, part = tid & 3;
        const float4* ep = (const float4*)(encT + (((long)b * 64 + s) << 10) + (q << 8) + (part << 6));
        const float4* hp = (const float4*)(hq + (part << 6));
        float dot = 0.f;
#pragma unroll
        for (int kk = 0; kk < 16; ++kk) {
          float4 e = ep[kk], a = hp[kk];
          dot += e.x * a.x + e.y * a.y + e.z * a.z + e.w * a.w;
        }
        dot += __shfl_xor(dot, 1);
        dot += __shfl_xor(dot, 2);
        if (part == 0) astore_f32(psc + (((b << 2) + q) << 6) + s, dot);
      }
    }
    gridbar(flags, seq); seq++;   // bar2

    // ========== Ph2c: softmax (redundant) + partial ctx (ALL blocks) =======
    {
      const int b = sb, q = sq;
      if (tid < 64) {
        int s = tid;
        float v = 0.f;
#pragma unroll
        for (int qq = 0; qq < 4; ++qq)
          v += __uint_as_float(aload_u32(psc + (((b << 2) + qq) << 6) + s));
        int len = xs_len[b];
        if (s >= len || v == 0.0f) v = -1e10f;
        float m = v;
#pragma unroll
        for (int off = 32; off; off >>= 1) m = fmaxf(m, __shfl_xor(m, off));
        float p = expf(v - m);
        float sum = p;
#pragma unroll
        for (int off = 32; off; off >>= 1) sum += __shfl_xor(sum, off);
        float a = p / sum;
        at_s[s] = a;
        if (q == 0) dout[ATT_OFF + ((long)b * T_ + t) * S_ + s] = a;
      }
      __syncthreads();
      // partial ctx over s in [16q, 16q+16)  (f32 encL)
      {
        const float* lp = encL + (((long)b * 64 + (q << 4)) << 10) + tid * 4;
        float c0 = 0.f, c1 = 0.f, c2 = 0.f, c3 = 0.f;
#pragma unroll
        for (int s2 = 0; s2 < 16; ++s2) {
          float a = at_s[(q << 4) + s2];
          float4 e = *(const float4*)(lp + (s2 << 10));
          c0 += a * e.x; c1 += a * e.y; c2 += a * e.z; c3 += a * e.w;
        }
        u64 w0 = ((u64)__float_as_uint(c1) << 32) | __float_as_uint(c0);
        u64 w1 = ((u64)__float_as_uint(c3) << 32) | __float_as_uint(c2);
        long o = (((long)(b << 2) + q) << 10) + tid * 4;
        astore_u64(ctxp + o, w0);
        astore_u64(ctxp + o + 2, w1);
      }
    }
    // bar3: pre-warm hh A-tiles (ready since bar2) for Ph3-slot blocks
    gb_arrive(flags, seq);
    if (isL2 || (isGH && t < T_ - 1)) {
      const u16* wa_h = hh_r + (long)(t + 1) * 65536 + (isGH ? kc * 512 : 0);
      const u16* wa_l = hl_r + (long)(t + 1) * 65536 + (isGH ? kc * 512 : 0);
      unsigned t0 = *(const u16*)(wa_h + g0w);
      unsigned t1 = *(const u16*)(wa_l + g0w);
      unsigned t2 = *(const u16*)(wa_h + g0w + 64);
      unsigned t3 = *(const u16*)(wa_l + g0w + 64);
      asm volatile("" :: "v"(t0), "v"(t1), "v"(t2), "v"(t3));
    }
    gb_wait(flags, seq); seq++;

    // ==== Ph3 slot: l2b finalize (192..223) CONCURRENT with gh(t+1) (96..191)
    if (isL2) {
      f32x4 acc[2][1];
      acc[0][0] = z4; acc[1][0] = z4;
      gemm_slab<1, 16>(hh_r + (long)(t + 1) * 65536, hl_r + (long)(t + 1) * 65536,
                       W_HI, W_LO, A_HI, A_LO, wm, wn, l15, kq, pr, ps, ao, acc);
      __syncthreads();
      float* cf = (float*)(L + 131072);  // 64x32 f32 = 8 KB
#pragma unroll
      for (int mi = 0; mi < 2; ++mi)
#pragma unroll
        for (int e = 0; e < 4; ++e) {
          int rr = (wm << 5) + (mi << 4) + (kq << 2) + e;
          int cc = (wn << 4) + l15;
          float a = 0.f;
#pragma unroll
          for (int qq = 0; qq < 4; ++qq)
            a += __uint_as_float(aload_u32(ctxp + (((long)(rr << 2) + qq) << 10) + n0 + cc));
          float v = tanhf(acc[mi][0][e] + a);
          if (t == T_ - 1) dout[CTF_OFF + (long)rr * 1024 + n0 + cc] = v;
          cf[rr * 32 + cc] = v;
        }
      __syncthreads();
#pragma unroll
      for (int qq2 = 0; qq2 < 2; ++qq2) {
        int g = tid + qq2 * 256;
        int b = g >> 3, colg = g & 7;
        u64 ph = 0, pl = 0;
#pragma unroll
        for (int ii = 0; ii < 4; ++ii) {
          float v = cf[b * 32 + colg * 4 + ii];
          u16 hi, lo;
          split2(v, &hi, &lo);
          ph |= (u64)hi << (16 * ii);
          pl |= (u64)lo << (16 * ii);
        }
        long o = (long)(t + 1) * 65536 + (long)b * 1024 + n0 + colg * 4;
        astore_u64(dctx_h + o, ph);
        astore_u64(dctx_l + o, pl);
      }
    } else if (isGH && t < T_ - 1) {
      // gh(t+1) = h_t @ whh^T : depends only on hh_r[t+1] (ready since bar2)
      f32x4 acc[2][2];
#pragma unroll
      for (int i = 0; i < 2; ++i)
#pragma unroll
        for (int j = 0; j < 2; ++j) acc[i][j] = z4;
      gemm_slab<2, 8>(hh_r + (long)(t + 1) * 65536 + kc * 512,
                      hl_r + (long)(t + 1) * 65536 + kc * 512,
                      W_HI, W_LO, A_HI, A_LO, wm, wn, l15, kq, pr, ps, ao, acc);
      epi_pack(ghp + (long)kc * 196608 + nt * 64, acc, wm, wn, l15, kq);
    }
    if (t < T_ - 1) { gridbar(flags, seq); }   // bar4
    seq++;
  }
}

// ---------------- in-place log-softmax over V per row ----------------
__device__ __forceinline__ void lse_comb(float& m, float& s, float mo, float so) {
  float M = fmaxf(m, mo);
  s = s * __expf(m - M) + so * __expf(mo - M);
  m = M;
}

__launch_bounds__(256)
__global__ void k_lsm(float* __restrict__ dout) {
  long base = (long)blockIdx.x * V_;
  int tid = threadIdx.x;
  float m = -3.0e38f, s = 0.f;
  for (int v = tid; v < V_; v += 256) {
    float x = dout[base + v];
    if (x > m) {
      s = s * __expf(m - x) + 1.f;
      m = x;
    } else {
      s += __expf(x - m);
    }
  }
#pragma unroll
  for (int off = 32; off; off >>= 1) {
    float mo = __shfl_xor(m, off), so = __shfl_xor(s, off);
    lse_comb(m, s, mo, so);
  }
  __shared__ float ms[4], ss[4];
  if ((tid & 63) == 0) { ms[tid >> 6] = m; ss[tid >> 6] = s; }
  __syncthreads();
  float M = ms[0], S = ss[0];
  for (int w2 = 1; w2 < 4; ++w2) lse_comb(M, S, ms[w2], ss[w2]);
  float logden = M + logf(S);
  for (int v = tid; v < V_; v += 256) dout[base + v] -= logden;
}

// ---------------- host launcher ----------------
extern "C" void kernel_launch(void* const* d_in, const int* in_sizes, int n_in,
                              void* d_out, int out_size, void* d_ws, size_t ws_size,
                              hipStream_t stream) {
  (void)in_sizes; (void)n_in; (void)out_size;
  const int* input = (const int*)d_in[0];
  const float* memory = (const float*)d_in[1];
  const float* enc = (const float*)d_in[2];
  const int* xs_len = (const int*)d_in[3];
  const float* emb = (const float*)d_in[4];
  const float* wih = (const float*)d_in[5];
  const float* whh = (const float*)d_in[6];
  const float* bih = (const float*)d_in[7];
  const float* bhh = (const float*)d_in[8];
  const float* l1 = (const float*)d_in[9];
  const float* l2 = (const float*)d_in[10];
  const float* wout = (const float*)d_in[11];
  const float* bout = (const float*)d_in[12];
  float* out = (float*)d_out;
  char* w = (char*)d_ws;

  size_t off = 0;
  auto alloc = [&](size_t bytes) {
    size_t o = off;
    off = (off + bytes + 255) & ~(size_t)255;
    return o;
  };
  const size_t N_WIH = 3072UL * 2048, N_WHH = 3072UL * 1024, N_L2 = 1024UL * 2048;
  const size_t N_L1 = 1024UL * 1024, N_ENC = 4096UL * 1024, N_WOUT = 32000UL * 1024;
  const size_t N_EMBX = 2048UL * 1024, N_ENCT = 4096UL * 1024;
  const size_t N_EMBI = 2048UL * 3072, N_ROT = 33UL * 65536;

  size_t o_wih_h = alloc(2 * N_WIH), o_wih_l = alloc(2 * N_WIH);
  size_t o_whh_h = alloc(2 * N_WHH), o_whh_l = alloc(2 * N_WHH);
  size_t o_l2_h = alloc(2 * N_L2), o_l2_l = alloc(2 * N_L2);
  size_t o_l1t_h = alloc(2 * N_L1), o_l1t_l = alloc(2 * N_L1);
  size_t o_ctx_h = alloc(2 * N_ROT), o_ctx_l = alloc(2 * N_ROT);
  size_t o_hh = alloc(2 * N_ROT), o_hl = alloc(2 * N_ROT);
  size_t o_gip = alloc(4 * 2 * 196608), o_ghp = alloc(4 * 2 * 196608);
  size_t o_psc = alloc(4 * 16384);
  size_t o_ctxp = alloc(4 * 262144);
  size_t o_bar = alloc(16384);
  size_t o_arena = alloc(2 * N_ENC * 2 + 2 * N_EMBX * 2 + 4 * N_EMBI + 4 * N_ENCT * 2);

  if (off > ws_size) {
    k_guard<<<1, 1, 0, stream>>>(out, 1.0e8f + (float)(ws_size >> 20));
    return;
  }

  u16* wih_h = (u16*)(w + o_wih_h);   u16* wih_l = (u16*)(w + o_wih_l);
  u16* whh_h = (u16*)(w + o_whh_h);   u16* whh_l = (u16*)(w + o_whh_l);
  u16* l2_h = (u16*)(w + o_l2_h);     u16* l2_l = (u16*)(w + o_l2_l);
  u16* l1t_h = (u16*)(w + o_l1t_h);   u16* l1t_l = (u16*)(w + o_l1t_l);
  u16* ctx_h = (u16*)(w + o_ctx_h);   u16* ctx_l = (u16*)(w + o_ctx_l);
  u16* hh_r = (u16*)(w + o_hh);       u16* hl_r = (u16*)(w + o_hl);
  float* gip = (float*)(w + o_gip);
  float* ghp = (float*)(w + o_ghp);
  float* psc = (float*)(w + o_psc);
  float* ctxp = (float*)(w + o_ctxp);
  unsigned* flags = (unsigned*)(w + o_bar);

  char* ar = w + o_arena;
  u16* enc_h = (u16*)ar;
  u16* enc_l = (u16*)(ar + 2 * N_ENC);
  u16* embx_h = (u16*)(ar + 4 * N_ENC);
  u16* embx_l = (u16*)(ar + 4 * N_ENC + 2 * N_EMBX);
  float* embi = (float*)(ar + 4 * N_ENC + 4 * N_EMBX);
  float* encT = (float*)(ar + 4 * N_ENC + 4 * N_EMBX + 4 * N_EMBI);
  float* encL = (float*)(ar + 4 * N_ENC + 4 * N_EMBX + 4 * N_EMBI + 4 * N_ENCT);
  u16* wout_b = (u16*)ar;  // overlays prep arena after k_rec

  hipFuncSetAttribute((const void*)k_rec, hipFuncAttributeMaxDynamicSharedMemorySize,
                      LDS_BYTES);

  // prep
  k_split<<<2048, 256, 0, stream>>>(wih, wih_h, wih_l, (int)N_WIH);
  k_split<<<2048, 256, 0, stream>>>(whh, whh_h, whh_l, (int)N_WHH);
  k_split<<<2048, 256, 0, stream>>>(l2, l2_h, l2_l, (int)N_L2);
  k_split<<<2048, 256, 0, stream>>>(enc, enc_h, enc_l, (int)N_ENC);
  k_l1t<<<256, 256, 0, stream>>>(l1, l1t_h, l1t_l);
  k_embx<<<2048, 256, 0, stream>>>(input, emb, embx_h, embx_l);
  k_h0<<<256, 256, 0, stream>>>(memory, hh_r, hl_r);
  hipMemsetAsync(ctx_h, 0, 131072, stream);  // dctx slot 0 = zeros
  hipMemsetAsync(ctx_l, 0, 131072, stream);
  hipMemsetAsync(flags, 0, 16384, stream);

  // encT = enc @ l1 ; encL = enc @ l2a^T ; embi = embx @ w_ih[:, :1024]^T
  k_gemm128<1, 0><<<256, 256, 0, stream>>>(enc_h, enc_l, l1t_h, l1t_l, encT, nullptr,
                                           32, 8, 1024, 1024, 1024, 1024);
  k_gemm128<1, 0><<<256, 256, 0, stream>>>(enc_h, enc_l, l2_h, l2_l, encL, nullptr,
                                           32, 8, 1024, 1024, 2048, 1024);
  k_gemm128<1, 0><<<384, 256, 0, stream>>>(embx_h, embx_l, wih_h, wih_l, embi, nullptr,
                                           16, 24, 1024, 1024, 2048, 3072);

  // persistent recurrence (256 blocks, 4 barriers/step, gh overlapped w/ Ph3)
  k_rec<<<NB_, 256, LDS_BYTES, stream>>>(embi, ctx_h, ctx_l, hh_r, hl_r, memory,
                                         wih_h, wih_l, whh_h, whh_l, l2_h, l2_l,
                                         gip, ghp, psc, ctxp, encT, encL,
                                         xs_len, bih, bhh, out, flags);

  // wout -> bf16 (overlays dead prep arena; runs after k_rec in stream order)
  k_tobf<<<4096, 256, 0, stream>>>(wout, wout_b, (int)N_WOUT);

  // logits = dctx_all @ w_out^T + b_out, scattered to [b][t][v]
  k_gemm128<0, 1><<<4000, 256, 0, stream>>>(ctx_h + 65536, nullptr, wout_b, nullptr,
                                            out, bout, 16, 250, 1024, 1024, 1024, 0);
  // in-place log-softmax per (b,t) row
  k_lsm<<<2048, 256, 0, stream>>>(out);
}

// Round 11
// 1959.605 us; speedup vs baseline: 1.0787x; 1.0787x over previous
//
#include <hip/hip_runtime.h>

// ---------------------------------------------------------------------------
// AttentionDecoder: B=64 T=32 S=64 H=1024 V=32000
// R11: k_rec reverted VERBATIM to R7 (best: 1394us). New work on the other
//      600us of the pipeline:
//  - k_gemmL (logits): global_load_lds width=16 staging with pre-swizzled
//    per-lane SOURCE + linear LDS dest (both-sides swizzle rule), XCD-
//    contiguous nt mapping (ctx L2-resident, wout once per XCD from L3).
//  - k_lsm: float4-vectorized read/write passes.
//  - prep: 4 k_split launches fused into one segmented kernel.
// ---------------------------------------------------------------------------

#define B_ 64
#define T_ 32
#define S_ 64
#define H_ 1024
#define V_ 32000
#define NB_ 256
#define LDS_BYTES 152064

#define HID_OFF 65536000L
#define ATT_OFF 65601536L
#define CTF_OFF 65732608L

typedef __attribute__((ext_vector_type(8))) short bf16x8;
typedef __attribute__((ext_vector_type(4))) float f32x4;
typedef __attribute__((ext_vector_type(4))) unsigned int u32x4;
typedef unsigned short u16;
typedef unsigned long long u64;

__device__ __forceinline__ u16 f2bf(float v) {
  unsigned int u = __float_as_uint(v);
  unsigned int r = (u + 0x7fffu + ((u >> 16) & 1u)) >> 16;  // RNE
  return (u16)r;
}
__device__ __forceinline__ float bf2f(u16 h) {
  return __uint_as_float(((unsigned int)h) << 16);
}
__device__ __forceinline__ void split2(float v, u16* hi, u16* lo) {
  u16 h = f2bf(v);
  *hi = h;
  *lo = f2bf(v - bf2f(h));
}

// ---- coherent-path (agent-scope relaxed atomic) helpers ----
__device__ __forceinline__ u64 aload_u64(const void* p) {
  return __hip_atomic_load((const u64*)p, __ATOMIC_RELAXED, __HIP_MEMORY_SCOPE_AGENT);
}
__device__ __forceinline__ unsigned aload_u32(const void* p) {
  return __hip_atomic_load((const unsigned*)p, __ATOMIC_RELAXED, __HIP_MEMORY_SCOPE_AGENT);
}
__device__ __forceinline__ void astore_u64(void* p, u64 v) {
  __hip_atomic_store((u64*)p, v, __ATOMIC_RELAXED, __HIP_MEMORY_SCOPE_AGENT);
}
__device__ __forceinline__ void astore_f32(float* p, float v) {
  __hip_atomic_store((unsigned*)p, __float_as_uint(v), __ATOMIC_RELAXED,
                     __HIP_MEMORY_SCOPE_AGENT);
}

// ---- async global->LDS (16B per lane; LDS dest = wave base + lane*16) ----
__device__ __forceinline__ void gll16(const u16* g, u16* l) {
  __builtin_amdgcn_global_load_lds(
      (const __attribute__((address_space(1))) void*)g,
      (__attribute__((address_space(3))) void*)l, 16, 0, 0);
}

// ---------------- conversion / prep kernels ----------------

__global__ void k_split4(const float* __restrict__ sA, u16* __restrict__ hA,
                         u16* __restrict__ lA, int nA,
                         const float* __restrict__ sB, u16* __restrict__ hB,
                         u16* __restrict__ lB, int nB,
                         const float* __restrict__ sC, u16* __restrict__ hC,
                         u16* __restrict__ lC, int nC,
                         const float* __restrict__ sD, u16* __restrict__ hD,
                         u16* __restrict__ lD, int nD) {
  int i = blockIdx.x * blockDim.x + threadIdx.x;
  int stride = gridDim.x * blockDim.x;
  int t1 = nA, t2 = nA + nB, t3 = t2 + nC, total = t3 + nD;
  for (; i < total; i += stride) {
    if (i < t1) split2(sA[i], &hA[i], &lA[i]);
    else if (i < t2) { int j = i - t1; split2(sB[j], &hB[j], &lB[j]); }
    else if (i < t3) { int j = i - t2; split2(sC[j], &hC[j], &lC[j]); }
    else { int j = i - t3; split2(sD[j], &hD[j], &lD[j]); }
  }
}

__global__ void k_tobf(const float* __restrict__ src, u16* __restrict__ dst, int n) {
  int i = blockIdx.x * blockDim.x + threadIdx.x;
  int stride = gridDim.x * blockDim.x;
  for (; i < n; i += stride) dst[i] = f2bf(src[i]);
}

// l1 (H,H) row-major [i][k] -> l1T hi/lo [k][i]
__global__ void k_l1t(const float* __restrict__ l1, u16* __restrict__ hi,
                      u16* __restrict__ lo) {
  __shared__ float tile[64][65];
  int it = blockIdx.x & 15, kt = blockIdx.x >> 4;
  for (int q = 0; q < 16; ++q) {
    int idx = q * 256 + threadIdx.x;
    int r = idx >> 6, c = idx & 63;
    tile[r][c] = l1[(long)(it * 64 + r) * H_ + kt * 64 + c];
  }
  __syncthreads();
  for (int q = 0; q < 16; ++q) {
    int idx = q * 256 + threadIdx.x;
    int r = idx >> 6, c = idx & 63;
    long o = (long)(kt * 64 + r) * H_ + it * 64 + c;
    split2(tile[c][r], &hi[o], &lo[o]);
  }
}

// gather embeddings: embx[t][b][k] hi/lo
__global__ void k_embx(const int* __restrict__ inp, const float* __restrict__ emb,
                       u16* __restrict__ hi, u16* __restrict__ lo) {
  int bt = blockIdx.x;
  int b = bt >> 5, t = bt & 31;
  int id = inp[b * T_ + t];
  const float* src = emb + (long)id * H_;
  long base = (long)(t * B_ + b) * H_;
  for (int k = threadIdx.x; k < H_; k += 256) split2(src[k], &hi[base + k], &lo[base + k]);
}

// h0 -> hh_r/hl_r slot 0
__global__ void k_h0(const float* __restrict__ mem, u16* __restrict__ hh,
                     u16* __restrict__ hl) {
  int i = blockIdx.x * 256 + threadIdx.x;  // 65536
  float v = mem[i];
  split2(v, &hh[i], &hl[i]);
}

__global__ void k_guard(float* out, float v) {
  if (blockIdx.x == 0 && threadIdx.x == 0) out[0] = v;
}

// ---------------- 128x128 tile GEMM (BK=32), split-bf16 (prep GEMMs) -------
template <int SPLIT>
__launch_bounds__(256)
__global__ void k_gemm128(const u16* __restrict__ Ah, const u16* __restrict__ Al,
                          const u16* __restrict__ Bh, const u16* __restrict__ Bl,
                          float* __restrict__ C, int Mtiles, int K, int Arow,
                          int Brow, int Crow) {
  int bx = blockIdx.x;
  int mt = bx % Mtiles, nt = bx / Mtiles;
  int m0 = mt * 128, n0 = nt * 128;

  __shared__ __attribute__((aligned(16))) u16 lds[(SPLIT ? 4 : 2) * 4096];
  char* L = (char*)lds;
  const int tid = threadIdx.x;
  const int lane = tid & 63, wid = tid >> 6;
  const int wm = wid & 1, wn = wid >> 1;
  const int l15 = lane & 15, kq = lane >> 4;

  f32x4 acc[4][4];
  const f32x4 z4 = {0.f, 0.f, 0.f, 0.f};
#pragma unroll
  for (int i = 0; i < 4; ++i)
#pragma unroll
    for (int j = 0; j < 4; ++j) acc[i][j] = z4;

  const int ksteps = K >> 5;
  for (int kt = 0; kt < ksteps; ++kt) {
    __syncthreads();
#pragma unroll
    for (int h2 = 0; h2 < 2; ++h2) {
      int r = (tid >> 2) + (h2 << 6);
      int slot = tid & 3;
      int so = ((slot ^ (r & 3)) << 4);
      long ga = (long)(m0 + r) * Arow + (kt << 5) + (slot << 3);
      long gb = (long)(n0 + r) * Brow + (kt << 5) + (slot << 3);
      *(u32x4*)(L + r * 64 + so) = *(const u32x4*)(Ah + ga);
      *(u32x4*)(L + 8192 + r * 64 + so) = *(const u32x4*)(Bh + gb);
      if (SPLIT) {
        *(u32x4*)(L + 16384 + r * 64 + so) = *(const u32x4*)(Al + ga);
        *(u32x4*)(L + 24576 + r * 64 + so) = *(const u32x4*)(Bl + gb);
      }
    }
    __syncthreads();
    bf16x8 aH[4], bH[4], aL[4], bL[4];
#pragma unroll
    for (int mi = 0; mi < 4; ++mi) {
      int r = (wm << 6) + (mi << 4) + l15;
      int off = r * 64 + ((kq ^ (r & 3)) << 4);
      aH[mi] = *(const bf16x8*)(L + off);
      if (SPLIT) aL[mi] = *(const bf16x8*)(L + 16384 + off);
    }
#pragma unroll
    for (int ni = 0; ni < 4; ++ni) {
      int c = (wn << 6) + (ni << 4) + l15;
      int off = c * 64 + ((kq ^ (c & 3)) << 4);
      bH[ni] = *(const bf16x8*)(L + 8192 + off);
      if (SPLIT) bL[ni] = *(const bf16x8*)(L + 24576 + off);
    }
#pragma unroll
    for (int mi = 0; mi < 4; ++mi)
#pragma unroll
      for (int ni = 0; ni < 4; ++ni) {
        acc[mi][ni] = __builtin_amdgcn_mfma_f32_16x16x32_bf16(aH[mi], bH[ni], acc[mi][ni], 0, 0, 0);
        if (SPLIT) {
          acc[mi][ni] = __builtin_amdgcn_mfma_f32_16x16x32_bf16(aL[mi], bH[ni], acc[mi][ni], 0, 0, 0);
          acc[mi][ni] = __builtin_amdgcn_mfma_f32_16x16x32_bf16(aH[mi], bL[ni], acc[mi][ni], 0, 0, 0);
        }
      }
  }
#pragma unroll
  for (int mi = 0; mi < 4; ++mi)
#pragma unroll
    for (int ni = 0; ni < 4; ++ni)
#pragma unroll
      for (int e = 0; e < 4; ++e) {
        int r = (wm << 6) + (mi << 4) + (kq << 2) + e;
        int c = (wn << 6) + (ni << 4) + l15;
        C[(long)(m0 + r) * Crow + n0 + c] = acc[mi][ni][e];
      }
}

// ---------------- logits GEMM: global_load_lds staging ----------------
// A: ctx bf16 [2048][1024]; B: wout bf16 [32000][1024]; C scatter + bias.
// LDS layout identical to k_gemm128 (row*64 + ((slot^(r&3))<<4)), produced by
// linear-dest global_load_lds with pre-swizzled per-lane SOURCE addresses.
__launch_bounds__(256)
__global__ void k_gemmL(const u16* __restrict__ A, const u16* __restrict__ Bw,
                        const float* __restrict__ bias, float* __restrict__ C) {
  int bx = blockIdx.x;
  // XCD-contiguous nt mapping: 4000 blocks, 8 XCDs, 500 wg each.
  int wg = (bx & 7) * 500 + (bx >> 3);
  int mt = wg & 15, nt = wg >> 4;
  int m0 = mt << 7, n0 = nt << 7;

  __shared__ __attribute__((aligned(16))) u16 lds[2 * 4096];  // A 8KB | B 8KB
  char* L = (char*)lds;
  const int tid = threadIdx.x;
  const int lane = tid & 63, wid = tid >> 6;
  const int wm = wid & 1, wn = wid >> 1;
  const int l15 = lane & 15, kq = lane >> 4;

  // staging decode: lane i of wave w covers LDS bytes [w*1024 + i*16).
  // dest row r = w*16 + i/4 (+64 for round 1), stored slot ss = i&3;
  // source slot s = ss ^ (r&3)  (both-sides swizzle).
  const int r8 = lane >> 2, ss = lane & 3;
  const int rA0 = (wid << 4) + r8, rA1 = rA0 + 64;
  const u16* gA0 = A + (long)(m0 + rA0) * 1024 + ((ss ^ (rA0 & 3)) << 3);
  const u16* gA1 = A + (long)(m0 + rA1) * 1024 + ((ss ^ (rA1 & 3)) << 3);
  const u16* gB0 = Bw + (long)(n0 + rA0) * 1024 + ((ss ^ (rA0 & 3)) << 3);
  const u16* gB1 = Bw + (long)(n0 + rA1) * 1024 + ((ss ^ (rA1 & 3)) << 3);
  u16* lA0 = (u16*)(L + (wid << 10));
  u16* lA1 = (u16*)(L + 4096 + (wid << 10));
  u16* lB0 = (u16*)(L + 8192 + (wid << 10));
  u16* lB1 = (u16*)(L + 12288 + (wid << 10));

  f32x4 acc[4][4];
  const f32x4 z4 = {0.f, 0.f, 0.f, 0.f};
#pragma unroll
  for (int i = 0; i < 4; ++i)
#pragma unroll
    for (int j = 0; j < 4; ++j) acc[i][j] = z4;

  for (int kt = 0; kt < 32; ++kt) {
    __syncthreads();
    gll16(gA0 + (kt << 5), lA0);
    gll16(gA1 + (kt << 5), lA1);
    gll16(gB0 + (kt << 5), lB0);
    gll16(gB1 + (kt << 5), lB1);
    __syncthreads();
    bf16x8 aF[4], bF[4];
#pragma unroll
    for (int mi = 0; mi < 4; ++mi) {
      int r = (wm << 6) + (mi << 4) + l15;
      aF[mi] = *(const bf16x8*)(L + r * 64 + ((kq ^ (r & 3)) << 4));
    }
#pragma unroll
    for (int ni = 0; ni < 4; ++ni) {
      int c = (wn << 6) + (ni << 4) + l15;
      bF[ni] = *(const bf16x8*)(L + 8192 + c * 64 + ((kq ^ (c & 3)) << 4));
    }
#pragma unroll
    for (int mi = 0; mi < 4; ++mi)
#pragma unroll
      for (int ni = 0; ni < 4; ++ni)
        acc[mi][ni] = __builtin_amdgcn_mfma_f32_16x16x32_bf16(aF[mi], bF[ni], acc[mi][ni], 0, 0, 0);
  }
#pragma unroll
  for (int mi = 0; mi < 4; ++mi)
#pragma unroll
    for (int ni = 0; ni < 4; ++ni)
#pragma unroll
      for (int e = 0; e < 4; ++e) {
        int r = (wm << 6) + (mi << 4) + (kq << 2) + e;
        int c = (wn << 6) + (ni << 4) + l15;
        int gm = m0 + r, gn = n0 + c;
        float v = acc[mi][ni][e] + bias[gn];
        C[((long)(gm & 63) * T_ + (gm >> 6)) * V_ + gn] = v;
      }
}

// ---------------- grid barrier (R7 verbatim) ----------------
__device__ __forceinline__ void gridbar(unsigned* flags, unsigned seq) {
  __syncthreads();
  if (threadIdx.x == 0)
    __hip_atomic_store(flags + blockIdx.x * 16, seq, __ATOMIC_RELEASE,
                       __HIP_MEMORY_SCOPE_AGENT);
  if (threadIdx.x < 64) {
    int l = threadIdx.x;
    for (;;) {
      unsigned a = __hip_atomic_load(flags + l * 16, __ATOMIC_RELAXED, __HIP_MEMORY_SCOPE_AGENT);
      unsigned b = __hip_atomic_load(flags + (l + 64) * 16, __ATOMIC_RELAXED, __HIP_MEMORY_SCOPE_AGENT);
      unsigned c = __hip_atomic_load(flags + (l + 128) * 16, __ATOMIC_RELAXED, __HIP_MEMORY_SCOPE_AGENT);
      unsigned d = __hip_atomic_load(flags + (l + 192) * 16, __ATOMIC_RELAXED, __HIP_MEMORY_SCOPE_AGENT);
      if (__all((a >= seq) & (b >= seq) & (c >= seq) & (d >= seq))) break;
      __builtin_amdgcn_s_sleep(1);
    }
  }
  __syncthreads();
}

// ---------------- persistent recurrence kernel (R7 verbatim) ----------------
__launch_bounds__(256)
__global__ void k_rec(const float* __restrict__ embi,
                      u16* __restrict__ dctx_h, u16* __restrict__ dctx_l,
                      u16* __restrict__ hh_r, u16* __restrict__ hl_r,
                      const float* __restrict__ memory,
                      const u16* __restrict__ wih_h, const u16* __restrict__ wih_l,
                      const u16* __restrict__ whh_h, const u16* __restrict__ whh_l,
                      const u16* __restrict__ l2_h, const u16* __restrict__ l2_l,
                      float* __restrict__ gip, float* __restrict__ ghp,
                      float* __restrict__ psc, float* __restrict__ ctxp,
                      const float* __restrict__ encT, const float* __restrict__ encL,
                      const int* __restrict__ xs_len,
                      const float* __restrict__ bih, const float* __restrict__ bhh,
                      float* __restrict__ dout, unsigned* flags) {
  extern __shared__ __attribute__((aligned(16))) char L[];
  char* W_HI = L;
  char* W_LO = L + 65536;
  char* A_HI = L + 131072;
  char* A_LO = L + 139264;
  float* hq = (float*)(L + 147456);
  float* at_s = (float*)(L + 148480);
  const int bx = blockIdx.x;
  const int tid = threadIdx.x;
  const int lane = tid & 63, wid = tid >> 6;
  const int wm = wid & 1, wn = wid >> 1;
  const int l15 = lane & 15, kq = lane >> 4;
  const f32x4 z4 = {0.f, 0.f, 0.f, 0.f};
  unsigned seq = 1;

  const int isGI = (bx < 96);
  const int isGH = (bx >= 96 && bx < 192);
  const int isL2 = (bx >= 192 && bx < 224);
  const int sb = bx >> 2;
  const int sq = bx & 3;
  int nt = 0, kc = 0, n0 = 0;
  const u16 *Wg_h = nullptr, *Wg_l = nullptr;
  int wrs = 0;
  if (isGI) {
    nt = bx % 48; kc = bx / 48;
    Wg_h = wih_h + 1024 + (long)nt * 64 * 2048 + kc * 512;
    Wg_l = wih_l + 1024 + (long)nt * 64 * 2048 + kc * 512;
    wrs = 2048;
  } else if (isGH) {
    int j2 = bx - 96;
    nt = j2 % 48; kc = j2 / 48;
    Wg_h = whh_h + (long)nt * 64 * 1024 + kc * 512;
    Wg_l = whh_l + (long)nt * 64 * 1024 + kc * 512;
    wrs = 1024;
  } else if (isL2) {
    n0 = (bx - 192) << 5;
    Wg_h = l2_h + 1024 + (long)n0 * 2048;
    Wg_l = l2_l + 1024 + (long)n0 * 2048;
    wrs = 2048;
  }

  if (isGI || isGH) {
    for (int e = tid; e < 4096; e += 256) {
      int st = e >> 8, r = (e >> 2) & 63, slot = e & 3;
      long g = (long)r * wrs + st * 32 + slot * 8;
      int o = st * 4096 + r * 64 + ((slot ^ (r & 3)) << 4);
      *(u32x4*)(W_HI + o) = *(const u32x4*)(Wg_h + g);
      *(u32x4*)(W_LO + o) = *(const u32x4*)(Wg_l + g);
    }
  } else if (isL2) {
    for (int e = tid; e < 4096; e += 256) {
      int st = e >> 7, r = (e >> 2) & 31, slot = e & 3;
      long g = (long)r * wrs + st * 32 + slot * 8;
      int o = st * 2048 + r * 64 + ((slot ^ (r & 3)) << 4);
      *(u32x4*)(W_HI + o) = *(const u32x4*)(Wg_h + g);
      *(u32x4*)(W_LO + o) = *(const u32x4*)(Wg_l + g);
    }
  }
  __syncthreads();

  float hpv = memory[sb * 1024 + sq * 256 + tid];

  const int pr = tid >> 2, ps = tid & 3;
  const int ao = pr * 64 + ((ps ^ (pr & 3)) << 4);

  for (int t = 0; t < T_; ++t) {
    // ================= Ph1: gates GEMMs (blocks 0..191) =================
    if (isGI || isGH) {
      const u16* Ah;
      const u16* Al;
      float* outp;
      if (isGI) {
        Ah = dctx_h + (long)t * 65536 + kc * 512;
        Al = dctx_l + (long)t * 65536 + kc * 512;
        outp = gip + (long)kc * 196608 + nt * 64;
      } else {
        Ah = hh_r + (long)t * 65536 + kc * 512;
        Al = hl_r + (long)t * 65536 + kc * 512;
        outp = ghp + (long)kc * 196608 + nt * 64;
      }
      const long g0 = (long)pr * 1024 + ps * 8;
      u32x4 ph0 = *(const u32x4*)(Ah + g0);
      u32x4 ph1 = *(const u32x4*)(Ah + g0 + 32);
      u32x4 pl0 = *(const u32x4*)(Al + g0);
      u32x4 pl1 = *(const u32x4*)(Al + g0 + 32);

      f32x4 acc[2][2];
#pragma unroll
      for (int i = 0; i < 2; ++i)
#pragma unroll
        for (int j = 0; j < 2; ++j) acc[i][j] = z4;

      for (int kt = 0; kt < 8; ++kt) {
        __syncthreads();
        *(u32x4*)(A_HI + ao) = ph0;
        *(u32x4*)(A_HI + 4096 + ao) = ph1;
        *(u32x4*)(A_LO + ao) = pl0;
        *(u32x4*)(A_LO + 4096 + ao) = pl1;
        __syncthreads();
        if (kt < 7) {
          long g = g0 + (kt + 1) * 64;
          ph0 = *(const u32x4*)(Ah + g);
          ph1 = *(const u32x4*)(Ah + g + 32);
          pl0 = *(const u32x4*)(Al + g);
          pl1 = *(const u32x4*)(Al + g + 32);
        }
#pragma unroll
        for (int sub = 0; sub < 2; ++sub) {
          const int stw = (kt * 2 + sub) * 4096;
          const int sta = sub * 4096;
          bf16x8 aH[2], aL[2], bH[2], bL[2];
#pragma unroll
          for (int mi = 0; mi < 2; ++mi) {
            int rr = (wm << 5) + (mi << 4) + l15;
            int off = rr * 64 + ((kq ^ (rr & 3)) << 4);
            aH[mi] = *(const bf16x8*)(A_HI + sta + off);
            aL[mi] = *(const bf16x8*)(A_LO + sta + off);
          }
#pragma unroll
          for (int ni = 0; ni < 2; ++ni) {
            int c = (wn << 5) + (ni << 4) + l15;
            int off = c * 64 + ((kq ^ (c & 3)) << 4);
            bH[ni] = *(const bf16x8*)(W_HI + stw + off);
            bL[ni] = *(const bf16x8*)(W_LO + stw + off);
          }
#pragma unroll
          for (int mi = 0; mi < 2; ++mi)
#pragma unroll
            for (int ni = 0; ni < 2; ++ni) {
              acc[mi][ni] = __builtin_amdgcn_mfma_f32_16x16x32_bf16(aH[mi], bH[ni], acc[mi][ni], 0, 0, 0);
              acc[mi][ni] = __builtin_amdgcn_mfma_f32_16x16x32_bf16(aL[mi], bH[ni], acc[mi][ni], 0, 0, 0);
              acc[mi][ni] = __builtin_amdgcn_mfma_f32_16x16x32_bf16(aH[mi], bL[ni], acc[mi][ni], 0, 0, 0);
            }
        }
      }
#pragma unroll
      for (int mi = 0; mi < 2; ++mi)
#pragma unroll
        for (int ni = 0; ni < 2; ++ni)
#pragma unroll
          for (int e = 0; e < 4; ++e) {
            int r = (wm << 5) + (mi << 4) + (kq << 2) + e;
            int c = (wn << 5) + (ni << 4) + l15;
            astore_f32(outp + (long)r * 3072 + c, acc[mi][ni][e]);
          }
    }
    gridbar(flags, seq); seq++;

    // ========== Ph2a: GRU quarter + partial scores (ALL 256 blocks) ========
    {
      const int b = sb, q = sq;
      const int j = (q << 8) + tid;
      const float* eb = embi + ((long)t * 64 + b) * 3072;
      float g0r = __uint_as_float(aload_u32(gip + b * 3072 + j));
      float g1r = __uint_as_float(aload_u32(gip + 196608 + b * 3072 + j));
      float g0z = __uint_as_float(aload_u32(gip + b * 3072 + 1024 + j));
      float g1z = __uint_as_float(aload_u32(gip + 196608 + b * 3072 + 1024 + j));
      float g0n = __uint_as_float(aload_u32(gip + b * 3072 + 2048 + j));
      float g1n = __uint_as_float(aload_u32(gip + 196608 + b * 3072 + 2048 + j));
      float h0r = __uint_as_float(aload_u32(ghp + b * 3072 + j));
      float h1r = __uint_as_float(aload_u32(ghp + 196608 + b * 3072 + j));
      float h0z = __uint_as_float(aload_u32(ghp + b * 3072 + 1024 + j));
      float h1z = __uint_as_float(aload_u32(ghp + 196608 + b * 3072 + 1024 + j));
      float h0n = __uint_as_float(aload_u32(ghp + b * 3072 + 2048 + j));
      float h1n = __uint_as_float(aload_u32(ghp + 196608 + b * 3072 + 2048 + j));
      float ir = eb[j] + g0r + g1r + bih[j];
      float iz = eb[1024 + j] + g0z + g1z + bih[1024 + j];
      float in2 = eb[2048 + j] + g0n + g1n + bih[2048 + j];
      float hr = h0r + h1r + bhh[j];
      float hz = h0z + h1z + bhh[1024 + j];
      float hn = h0n + h1n + bhh[2048 + j];
      float r = 1.f / (1.f + expf(-(ir + hr)));
      float z = 1.f / (1.f + expf(-(iz + hz)));
      float n = tanhf(in2 + r * hn);
      float h = (1.f - z) * n + z * hpv;
      hpv = h;
      hq[tid] = h;
      if (t == T_ - 1) dout[HID_OFF + (long)b * 1024 + j] = h;
      __syncthreads();
      if (tid < 64) {
        u64 ph = 0, pl = 0;
#pragma unroll
        for (int ii = 0; ii < 4; ++ii) {
          u16 hi, lo;
          split2(hq[tid * 4 + ii], &hi, &lo);
          ph |= (u64)hi << (16 * ii);
          pl |= (u64)lo << (16 * ii);
        }
        long o = (long)(t + 1) * 65536 + (long)b * 1024 + (q << 8) + tid * 4;
        astore_u64(hh_r + o, ph);
        astore_u64(hl_r + o, pl);
      }
      {
        int s = tid >> 2, part = tid & 3;
        const float4* ep = (const float4*)(encT + (((long)b * 64 + s) << 10) + (q << 8) + (part << 6));
        const float4* hp = (const float4*)(hq + (part << 6));
        float dot = 0.f;
#pragma unroll
        for (int kk = 0; kk < 16; ++kk) {
          float4 e = ep[kk], a = hp[kk];
          dot += e.x * a.x + e.y * a.y + e.z * a.z + e.w * a.w;
        }
        dot += __shfl_xor(dot, 1);
        dot += __shfl_xor(dot, 2);
        if (part == 0) astore_f32(psc + (((b << 2) + q) << 6) + s, dot);
      }
    }
    gridbar(flags, seq); seq++;

    // ========== Ph2c: softmax (redundant) + partial ctx (ALL blocks) =======
    {
      const int b = sb, q = sq;
      if (tid < 64) {
        int s = tid;
        float v = 0.f;
#pragma unroll
        for (int qq = 0; qq < 4; ++qq)
          v += __uint_as_float(aload_u32(psc + (((b << 2) + qq) << 6) + s));
        int len = xs_len[b];
        if (s >= len || v == 0.0f) v = -1e10f;
        float m = v;
#pragma unroll
        for (int off = 32; off; off >>= 1) m = fmaxf(m, __shfl_xor(m, off));
        float p = expf(v - m);
        float sum = p;
#pragma unroll
        for (int off = 32; off; off >>= 1) sum += __shfl_xor(sum, off);
        float a = p / sum;
        at_s[s] = a;
        if (q == 0) dout[ATT_OFF + ((long)b * T_ + t) * S_ + s] = a;
      }
      __syncthreads();
      {
        const float* lp = encL + (((long)b * 64 + (q << 4)) << 10) + tid * 4;
        float c0 = 0.f, c1 = 0.f, c2 = 0.f, c3 = 0.f;
#pragma unroll
        for (int s2 = 0; s2 < 16; ++s2) {
          float a = at_s[(q << 4) + s2];
          float4 e = *(const float4*)(lp + (s2 << 10));
          c0 += a * e.x; c1 += a * e.y; c2 += a * e.z; c3 += a * e.w;
        }
        u64 w0 = ((u64)__float_as_uint(c1) << 32) | __float_as_uint(c0);
        u64 w1 = ((u64)__float_as_uint(c3) << 32) | __float_as_uint(c2);
        long o = (((long)(b << 2) + q) << 10) + tid * 4;
        astore_u64(ctxp + o, w0);
        astore_u64(ctxp + o + 2, w1);
      }
    }
    gridbar(flags, seq); seq++;

    // ========== Ph3: dctx[t+1] = tanh(Σq ctxp + h@l2b^T) (blocks 192..223) ==
    if (isL2) {
      const u16* Ah = hh_r + (long)(t + 1) * 65536;
      const u16* Al = hl_r + (long)(t + 1) * 65536;
      const long g0 = (long)pr * 1024 + ps * 8;
      u32x4 ph0 = *(const u32x4*)(Ah + g0);
      u32x4 ph1 = *(const u32x4*)(Ah + g0 + 32);
      u32x4 pl0 = *(const u32x4*)(Al + g0);
      u32x4 pl1 = *(const u32x4*)(Al + g0 + 32);

      f32x4 acc[2];
      acc[0] = z4; acc[1] = z4;
      for (int kt = 0; kt < 16; ++kt) {
        __syncthreads();
        *(u32x4*)(A_HI + ao) = ph0;
        *(u32x4*)(A_HI + 4096 + ao) = ph1;
        *(u32x4*)(A_LO + ao) = pl0;
        *(u32x4*)(A_LO + 4096 + ao) = pl1;
        __syncthreads();
        if (kt < 15) {
          long g = g0 + (kt + 1) * 64;
          ph0 = *(const u32x4*)(Ah + g);
          ph1 = *(const u32x4*)(Ah + g + 32);
          pl0 = *(const u32x4*)(Al + g);
          pl1 = *(const u32x4*)(Al + g + 32);
        }
#pragma unroll
        for (int sub = 0; sub < 2; ++sub) {
          const int stw = (kt * 2 + sub) * 2048;
          const int sta = sub * 4096;
          bf16x8 aH[2], aL[2], bH, bL;
#pragma unroll
          for (int mi = 0; mi < 2; ++mi) {
            int rr = (wm << 5) + (mi << 4) + l15;
            int off = rr * 64 + ((kq ^ (rr & 3)) << 4);
            aH[mi] = *(const bf16x8*)(A_HI + sta + off);
            aL[mi] = *(const bf16x8*)(A_LO + sta + off);
          }
          {
            int c = (wn << 4) + l15;
            int off = c * 64 + ((kq ^ (c & 3)) << 4);
            bH = *(const bf16x8*)(W_HI + stw + off);
            bL = *(const bf16x8*)(W_LO + stw + off);
          }
#pragma unroll
          for (int mi = 0; mi < 2; ++mi) {
            acc[mi] = __builtin_amdgcn_mfma_f32_16x16x32_bf16(aH[mi], bH, acc[mi], 0, 0, 0);
            acc[mi] = __builtin_amdgcn_mfma_f32_16x16x32_bf16(aL[mi], bH, acc[mi], 0, 0, 0);
            acc[mi] = __builtin_amdgcn_mfma_f32_16x16x32_bf16(aH[mi], bL, acc[mi], 0, 0, 0);
          }
        }
      }
      __syncthreads();
      float* cf = (float*)(L + 131072);
#pragma unroll
      for (int mi = 0; mi < 2; ++mi)
#pragma unroll
        for (int e = 0; e < 4; ++e) {
          int rr = (wm << 5) + (mi << 4) + (kq << 2) + e;
          int cc = (wn << 4) + l15;
          float a = 0.f;
#pragma unroll
          for (int qq = 0; qq < 4; ++qq)
            a += __uint_as_float(aload_u32(ctxp + (((long)(rr << 2) + qq) << 10) + n0 + cc));
          float v = tanhf(acc[mi][e] + a);
          if (t == T_ - 1) dout[CTF_OFF + (long)rr * 1024 + n0 + cc] = v;
          cf[rr * 32 + cc] = v;
        }
      __syncthreads();
#pragma unroll
      for (int qq2 = 0; qq2 < 2; ++qq2) {
        int g = tid + qq2 * 256;
        int b = g >> 3, colg = g & 7;
        u64 ph = 0, pl = 0;
#pragma unroll
        for (int ii = 0; ii < 4; ++ii) {
          float v = cf[b * 32 + colg * 4 + ii];
          u16 hi, lo;
          split2(v, &hi, &lo);
          ph |= (u64)hi << (16 * ii);
          pl |= (u64)lo << (16 * ii);
        }
        long o = (long)(t + 1) * 65536 + (long)b * 1024 + n0 + colg * 4;
        astore_u64(dctx_h + o, ph);
        astore_u64(dctx_l + o, pl);
      }
    }
    if (t < T_ - 1) { gridbar(flags, seq); }
    seq++;
  }
}

// ---------------- in-place log-softmax over V per row (float4) ----------------
__device__ __forceinline__ void lse_comb(float& m, float& s, float mo, float so) {
  float M = fmaxf(m, mo);
  s = s * __expf(m - M) + so * __expf(mo - M);
  m = M;
}
__device__ __forceinline__ void lse_push(float& m, float& s, float x) {
  if (x > m) {
    s = s * __expf(m - x) + 1.f;
    m = x;
  } else {
    s += __expf(x - m);
  }
}

__launch_bounds__(256)
__global__ void k_lsm(float* __restrict__ dout) {
  long base = (long)blockIdx.x * V_;
  int tid = threadIdx.x;
  float m = -3.0e38f, s = 0.f;
  const float4* p4 = (const float4*)(dout + base);
#pragma unroll 4
  for (int it = 0; it < 31; ++it) {
    float4 x = p4[it * 256 + tid];
    lse_push(m, s, x.x); lse_push(m, s, x.y);
    lse_push(m, s, x.z); lse_push(m, s, x.w);
  }
  if (tid < 64) {
    float4 x = p4[7936 + tid];
    lse_push(m, s, x.x); lse_push(m, s, x.y);
    lse_push(m, s, x.z); lse_push(m, s, x.w);
  }
#pragma unroll
  for (int off = 32; off; off >>= 1) {
    float mo = __shfl_xor(m, off), so = __shfl_xor(s, off);
    lse_comb(m, s, mo, so);
  }
  __shared__ float ms[4], ss[4];
  if ((tid & 63) == 0) { ms[tid >> 6] = m; ss[tid >> 6] = s; }
  __syncthreads();
  float M = ms[0], S = ss[0];
  for (int w2 = 1; w2 < 4; ++w2) lse_comb(M, S, ms[w2], ss[w2]);
  float logden = M + logf(S);
  float4* q4 = (float4*)(dout + base);
#pragma unroll 4
  for (int it = 0; it < 31; ++it) {
    float4 x = q4[it * 256 + tid];
    x.x -= logden; x.y -= logden; x.z -= logden; x.w -= logden;
    q4[it * 256 + tid] = x;
  }
  if (tid < 64) {
    float4 x = q4[7936 + tid];
    x.x -= logden; x.y -= logden; x.z -= logden; x.w -= logden;
    q4[7936 + tid] = x;
  }
}

// ---------------- host launcher ----------------
extern "C" void kernel_launch(void* const* d_in, const int* in_sizes, int n_in,
                              void* d_out, int out_size, void* d_ws, size_t ws_size,
                              hipStream_t stream) {
  (void)in_sizes; (void)n_in; (void)out_size;
  const int* input = (const int*)d_in[0];
  const float* memory = (const float*)d_in[1];
  const float* enc = (const float*)d_in[2];
  const int* xs_len = (const int*)d_in[3];
  const float* emb = (const float*)d_in[4];
  const float* wih = (const float*)d_in[5];
  const float* whh = (const float*)d_in[6];
  const float* bih = (const float*)d_in[7];
  const float* bhh = (const float*)d_in[8];
  const float* l1 = (const float*)d_in[9];
  const float* l2 = (const float*)d_in[10];
  const float* wout = (const float*)d_in[11];
  const float* bout = (const float*)d_in[12];
  float* out = (float*)d_out;
  char* w = (char*)d_ws;

  size_t off = 0;
  auto alloc = [&](size_t bytes) {
    size_t o = off;
    off = (off + bytes + 255) & ~(size_t)255;
    return o;
  };
  const size_t N_WIH = 3072UL * 2048, N_WHH = 3072UL * 1024, N_L2 = 1024UL * 2048;
  const size_t N_L1 = 1024UL * 1024, N_ENC = 4096UL * 1024, N_WOUT = 32000UL * 1024;
  const size_t N_EMBX = 2048UL * 1024, N_ENCT = 4096UL * 1024;
  const size_t N_EMBI = 2048UL * 3072, N_ROT = 33UL * 65536;

  size_t o_wih_h = alloc(2 * N_WIH), o_wih_l = alloc(2 * N_WIH);
  size_t o_whh_h = alloc(2 * N_WHH), o_whh_l = alloc(2 * N_WHH);
  size_t o_l2_h = alloc(2 * N_L2), o_l2_l = alloc(2 * N_L2);
  size_t o_l1t_h = alloc(2 * N_L1), o_l1t_l = alloc(2 * N_L1);
  size_t o_ctx_h = alloc(2 * N_ROT), o_ctx_l = alloc(2 * N_ROT);
  size_t o_hh = alloc(2 * N_ROT), o_hl = alloc(2 * N_ROT);
  size_t o_gip = alloc(4 * 2 * 196608), o_ghp = alloc(4 * 2 * 196608);
  size_t o_psc = alloc(4 * 16384);
  size_t o_ctxp = alloc(4 * 262144);
  size_t o_bar = alloc(16384);
  size_t o_arena = alloc(2 * N_ENC * 2 + 2 * N_EMBX * 2 + 4 * N_EMBI + 4 * N_ENCT * 2);

  if (off > ws_size) {
    k_guard<<<1, 1, 0, stream>>>(out, 1.0e8f + (float)(ws_size >> 20));
    return;
  }

  u16* wih_h = (u16*)(w + o_wih_h);   u16* wih_l = (u16*)(w + o_wih_l);
  u16* whh_h = (u16*)(w + o_whh_h);   u16* whh_l = (u16*)(w + o_whh_l);
  u16* l2_h = (u16*)(w + o_l2_h);     u16* l2_l = (u16*)(w + o_l2_l);
  u16* l1t_h = (u16*)(w + o_l1t_h);   u16* l1t_l = (u16*)(w + o_l1t_l);
  u16* ctx_h = (u16*)(w + o_ctx_h);   u16* ctx_l = (u16*)(w + o_ctx_l);
  u16* hh_r = (u16*)(w + o_hh);       u16* hl_r = (u16*)(w + o_hl);
  float* gip = (float*)(w + o_gip);
  float* ghp = (float*)(w + o_ghp);
  float* psc = (float*)(w + o_psc);
  float* ctxp = (float*)(w + o_ctxp);
  unsigned* flags = (unsigned*)(w + o_bar);

  char* ar = w + o_arena;
  u16* enc_h = (u16*)ar;
  u16* enc_l = (u16*)(ar + 2 * N_ENC);
  u16* embx_h = (u16*)(ar + 4 * N_ENC);
  u16* embx_l = (u16*)(ar + 4 * N_ENC + 2 * N_EMBX);
  float* embi = (float*)(ar + 4 * N_ENC + 4 * N_EMBX);
  float* encT = (float*)(ar + 4 * N_ENC + 4 * N_EMBX + 4 * N_EMBI);
  float* encL = (float*)(ar + 4 * N_ENC + 4 * N_EMBX + 4 * N_EMBI + 4 * N_ENCT);
  u16* wout_b = (u16*)ar;  // overlays prep arena after k_rec

  hipFuncSetAttribute((const void*)k_rec, hipFuncAttributeMaxDynamicSharedMemorySize,
                      LDS_BYTES);

  // prep (fused splits)
  k_split4<<<4096, 256, 0, stream>>>(wih, wih_h, wih_l, (int)N_WIH,
                                     whh, whh_h, whh_l, (int)N_WHH,
                                     l2, l2_h, l2_l, (int)N_L2,
                                     enc, enc_h, enc_l, (int)N_ENC);
  k_l1t<<<256, 256, 0, stream>>>(l1, l1t_h, l1t_l);
  k_embx<<<2048, 256, 0, stream>>>(input, emb, embx_h, embx_l);
  k_h0<<<256, 256, 0, stream>>>(memory, hh_r, hl_r);
  hipMemsetAsync(ctx_h, 0, 131072, stream);
  hipMemsetAsync(ctx_l, 0, 131072, stream);
  hipMemsetAsync(flags, 0, 16384, stream);

  // encT = enc @ l1 ; encL = enc @ l2a^T ; embi = embx @ w_ih[:, :1024]^T
  k_gemm128<1><<<256, 256, 0, stream>>>(enc_h, enc_l, l1t_h, l1t_l, encT,
                                        32, 1024, 1024, 1024, 1024);
  k_gemm128<1><<<256, 256, 0, stream>>>(enc_h, enc_l, l2_h, l2_l, encL,
                                        32, 1024, 1024, 2048, 1024);
  k_gemm128<1><<<384, 256, 0, stream>>>(embx_h, embx_l, wih_h, wih_l, embi,
                                        16, 1024, 1024, 2048, 3072);

  // persistent recurrence (R7 verbatim: 256 blocks, 4 barriers/step)
  k_rec<<<NB_, 256, LDS_BYTES, stream>>>(embi, ctx_h, ctx_l, hh_r, hl_r, memory,
                                         wih_h, wih_l, whh_h, whh_l, l2_h, l2_l,
                                         gip, ghp, psc, ctxp, encT, encL,
                                         xs_len, bih, bhh, out, flags);

  // wout -> bf16 (overlays dead prep arena; after k_rec in stream order)
  k_tobf<<<4096, 256, 0, stream>>>(wout, wout_b, (int)N_WOUT);

  // logits GEMM (global_load_lds staging, XCD-contiguous nt)
  k_gemmL<<<4000, 256, 0, stream>>>(ctx_h + 65536, wout_b, bout, out);

  // in-place log-softmax per (b,t) row
  k_lsm<<<2048, 256, 0, stream>>>(out);
}

// Round 12
// 1948.384 us; speedup vs baseline: 1.0849x; 1.0058x over previous
//
#include <hip/hip_runtime.h>

// ---------------------------------------------------------------------------
// AttentionDecoder: B=64 T=32 S=64 H=1024 V=32000
// R12: k_rec untouched (R7/R11 verbatim, 1416us). Tail work:
//  - k_gemmG: prep GEMMs (encT/encL/embi) now use global_load_lds width=16
//    staging (pre-swizzled source + linear LDS dest), split-bf16 3-term MFMA.
//  - k_gemmL epilogue computes per-(row,tile) partial LSE (m,s) from
//    registers -> psum[2048][256]; k_lsm loses its 262MB read pass (combines
//    250 partials + subtract pass only).
// ---------------------------------------------------------------------------

#define B_ 64
#define T_ 32
#define S_ 64
#define H_ 1024
#define V_ 32000
#define NB_ 256
#define LDS_BYTES 152064

#define HID_OFF 65536000L
#define ATT_OFF 65601536L
#define CTF_OFF 65732608L

typedef __attribute__((ext_vector_type(8))) short bf16x8;
typedef __attribute__((ext_vector_type(4))) float f32x4;
typedef __attribute__((ext_vector_type(4))) unsigned int u32x4;
typedef unsigned short u16;
typedef unsigned long long u64;

__device__ __forceinline__ u16 f2bf(float v) {
  unsigned int u = __float_as_uint(v);
  unsigned int r = (u + 0x7fffu + ((u >> 16) & 1u)) >> 16;  // RNE
  return (u16)r;
}
__device__ __forceinline__ float bf2f(u16 h) {
  return __uint_as_float(((unsigned int)h) << 16);
}
__device__ __forceinline__ void split2(float v, u16* hi, u16* lo) {
  u16 h = f2bf(v);
  *hi = h;
  *lo = f2bf(v - bf2f(h));
}

// ---- coherent-path (agent-scope relaxed atomic) helpers ----
__device__ __forceinline__ u64 aload_u64(const void* p) {
  return __hip_atomic_load((const u64*)p, __ATOMIC_RELAXED, __HIP_MEMORY_SCOPE_AGENT);
}
__device__ __forceinline__ unsigned aload_u32(const void* p) {
  return __hip_atomic_load((const unsigned*)p, __ATOMIC_RELAXED, __HIP_MEMORY_SCOPE_AGENT);
}
__device__ __forceinline__ void astore_u64(void* p, u64 v) {
  __hip_atomic_store((u64*)p, v, __ATOMIC_RELAXED, __HIP_MEMORY_SCOPE_AGENT);
}
__device__ __forceinline__ void astore_f32(float* p, float v) {
  __hip_atomic_store((unsigned*)p, __float_as_uint(v), __ATOMIC_RELAXED,
                     __HIP_MEMORY_SCOPE_AGENT);
}

// ---- async global->LDS (16B/lane; dest = wave-uniform base + lane*16) ----
__device__ __forceinline__ void gll16(const u16* g, u16* l) {
  __builtin_amdgcn_global_load_lds(
      (const __attribute__((address_space(1))) void*)g,
      (__attribute__((address_space(3))) void*)l, 16, 0, 0);
}

// ---------------- conversion / prep kernels ----------------

__global__ void k_split4(const float* __restrict__ sA, u16* __restrict__ hA,
                         u16* __restrict__ lA, int nA,
                         const float* __restrict__ sB, u16* __restrict__ hB,
                         u16* __restrict__ lB, int nB,
                         const float* __restrict__ sC, u16* __restrict__ hC,
                         u16* __restrict__ lC, int nC,
                         const float* __restrict__ sD, u16* __restrict__ hD,
                         u16* __restrict__ lD, int nD) {
  int i = blockIdx.x * blockDim.x + threadIdx.x;
  int stride = gridDim.x * blockDim.x;
  int t1 = nA, t2 = nA + nB, t3 = t2 + nC, total = t3 + nD;
  for (; i < total; i += stride) {
    if (i < t1) split2(sA[i], &hA[i], &lA[i]);
    else if (i < t2) { int j = i - t1; split2(sB[j], &hB[j], &lB[j]); }
    else if (i < t3) { int j = i - t2; split2(sC[j], &hC[j], &lC[j]); }
    else { int j = i - t3; split2(sD[j], &hD[j], &lD[j]); }
  }
}

__global__ void k_tobf(const float* __restrict__ src, u16* __restrict__ dst, int n) {
  int i = blockIdx.x * blockDim.x + threadIdx.x;
  int stride = gridDim.x * blockDim.x;
  for (; i < n; i += stride) dst[i] = f2bf(src[i]);
}

// l1 (H,H) row-major [i][k] -> l1T hi/lo [k][i]
__global__ void k_l1t(const float* __restrict__ l1, u16* __restrict__ hi,
                      u16* __restrict__ lo) {
  __shared__ float tile[64][65];
  int it = blockIdx.x & 15, kt = blockIdx.x >> 4;
  for (int q = 0; q < 16; ++q) {
    int idx = q * 256 + threadIdx.x;
    int r = idx >> 6, c = idx & 63;
    tile[r][c] = l1[(long)(it * 64 + r) * H_ + kt * 64 + c];
  }
  __syncthreads();
  for (int q = 0; q < 16; ++q) {
    int idx = q * 256 + threadIdx.x;
    int r = idx >> 6, c = idx & 63;
    long o = (long)(kt * 64 + r) * H_ + it * 64 + c;
    split2(tile[c][r], &hi[o], &lo[o]);
  }
}

// gather embeddings: embx[t][b][k] hi/lo
__global__ void k_embx(const int* __restrict__ inp, const float* __restrict__ emb,
                       u16* __restrict__ hi, u16* __restrict__ lo) {
  int bt = blockIdx.x;
  int b = bt >> 5, t = bt & 31;
  int id = inp[b * T_ + t];
  const float* src = emb + (long)id * H_;
  long base = (long)(t * B_ + b) * H_;
  for (int k = threadIdx.x; k < H_; k += 256) split2(src[k], &hi[base + k], &lo[base + k]);
}

// h0 -> hh_r/hl_r slot 0
__global__ void k_h0(const float* __restrict__ mem, u16* __restrict__ hh,
                     u16* __restrict__ hl) {
  int i = blockIdx.x * 256 + threadIdx.x;  // 65536
  float v = mem[i];
  split2(v, &hh[i], &hl[i]);
}

__global__ void k_guard(float* out, float v) {
  if (blockIdx.x == 0 && threadIdx.x == 0) out[0] = v;
}

// ------- prep GEMM: 128x128 tile, K=1024, split-bf16, gll16 staging -------
// LDS: [0,8K) A_hi | [8K,16K) B_hi | [16K,24K) A_lo | [24K,32K) B_lo
__launch_bounds__(256)
__global__ void k_gemmG(const u16* __restrict__ Ah, const u16* __restrict__ Al,
                        const u16* __restrict__ Bh, const u16* __restrict__ Bl,
                        float* __restrict__ C, int Mtiles, int Arow, int Brow,
                        int Crow) {
  int bx = blockIdx.x;
  int mt = bx % Mtiles, nt = bx / Mtiles;
  int m0 = mt << 7, n0 = nt << 7;

  __shared__ __attribute__((aligned(16))) u16 lds[4 * 4096];  // 32 KB
  char* L = (char*)lds;
  const int tid = threadIdx.x;
  const int lane = tid & 63, wid = tid >> 6;
  const int wm = wid & 1, wn = wid >> 1;
  const int l15 = lane & 15, kq = lane >> 4;

  // staging: lane i of wave w fills 16B at region + w*1024 + i*16.
  // dest row r = w*16 + i/4 (round0) / +64 (round1); stored slot = i&3;
  // source slot = stored ^ (r&3)  (both-sides swizzle).
  const int r8 = lane >> 2, ss = lane & 3;
  const int rA0 = (wid << 4) + r8, rA1 = rA0 + 64;
  const int sw0 = (ss ^ (rA0 & 3)) << 3, sw1 = (ss ^ (rA1 & 3)) << 3;
  const u16* gAh0 = Ah + (long)(m0 + rA0) * Arow + sw0;
  const u16* gAh1 = Ah + (long)(m0 + rA1) * Arow + sw1;
  const u16* gAl0 = Al + (long)(m0 + rA0) * Arow + sw0;
  const u16* gAl1 = Al + (long)(m0 + rA1) * Arow + sw1;
  const u16* gBh0 = Bh + (long)(n0 + rA0) * Brow + sw0;
  const u16* gBh1 = Bh + (long)(n0 + rA1) * Brow + sw1;
  const u16* gBl0 = Bl + (long)(n0 + rA0) * Brow + sw0;
  const u16* gBl1 = Bl + (long)(n0 + rA1) * Brow + sw1;
  u16* dAh0 = (u16*)(L + (wid << 10));
  u16* dAh1 = (u16*)(L + 4096 + (wid << 10));
  u16* dBh0 = (u16*)(L + 8192 + (wid << 10));
  u16* dBh1 = (u16*)(L + 12288 + (wid << 10));
  u16* dAl0 = (u16*)(L + 16384 + (wid << 10));
  u16* dAl1 = (u16*)(L + 20480 + (wid << 10));
  u16* dBl0 = (u16*)(L + 24576 + (wid << 10));
  u16* dBl1 = (u16*)(L + 28672 + (wid << 10));

  f32x4 acc[4][4];
  const f32x4 z4 = {0.f, 0.f, 0.f, 0.f};
#pragma unroll
  for (int i = 0; i < 4; ++i)
#pragma unroll
    for (int j = 0; j < 4; ++j) acc[i][j] = z4;

  for (int kt = 0; kt < 32; ++kt) {
    __syncthreads();
    int ko = kt << 5;
    gll16(gAh0 + ko, dAh0);
    gll16(gAh1 + ko, dAh1);
    gll16(gBh0 + ko, dBh0);
    gll16(gBh1 + ko, dBh1);
    gll16(gAl0 + ko, dAl0);
    gll16(gAl1 + ko, dAl1);
    gll16(gBl0 + ko, dBl0);
    gll16(gBl1 + ko, dBl1);
    __syncthreads();
    bf16x8 aH[4], bH[4], aL[4], bL[4];
#pragma unroll
    for (int mi = 0; mi < 4; ++mi) {
      int r = (wm << 6) + (mi << 4) + l15;
      int off = r * 64 + ((kq ^ (r & 3)) << 4);
      aH[mi] = *(const bf16x8*)(L + off);
      aL[mi] = *(const bf16x8*)(L + 16384 + off);
    }
#pragma unroll
    for (int ni = 0; ni < 4; ++ni) {
      int c = (wn << 6) + (ni << 4) + l15;
      int off = c * 64 + ((kq ^ (c & 3)) << 4);
      bH[ni] = *(const bf16x8*)(L + 8192 + off);
      bL[ni] = *(const bf16x8*)(L + 24576 + off);
    }
#pragma unroll
    for (int mi = 0; mi < 4; ++mi)
#pragma unroll
      for (int ni = 0; ni < 4; ++ni) {
        acc[mi][ni] = __builtin_amdgcn_mfma_f32_16x16x32_bf16(aH[mi], bH[ni], acc[mi][ni], 0, 0, 0);
        acc[mi][ni] = __builtin_amdgcn_mfma_f32_16x16x32_bf16(aL[mi], bH[ni], acc[mi][ni], 0, 0, 0);
        acc[mi][ni] = __builtin_amdgcn_mfma_f32_16x16x32_bf16(aH[mi], bL[ni], acc[mi][ni], 0, 0, 0);
      }
  }
#pragma unroll
  for (int mi = 0; mi < 4; ++mi)
#pragma unroll
    for (int ni = 0; ni < 4; ++ni)
#pragma unroll
      for (int e = 0; e < 4; ++e) {
        int r = (wm << 6) + (mi << 4) + (kq << 2) + e;
        int c = (wn << 6) + (ni << 4) + l15;
        C[(long)(m0 + r) * Crow + n0 + c] = acc[mi][ni][e];
      }
}

__device__ __forceinline__ void lse_comb(float& m, float& s, float mo, float so) {
  float M = fmaxf(m, mo);
  s = s * __expf(m - M) + so * __expf(mo - M);
  m = M;
}

// ---------------- logits GEMM + partial-LSE epilogue ----------------
__launch_bounds__(256)
__global__ void k_gemmL(const u16* __restrict__ A, const u16* __restrict__ Bw,
                        const float* __restrict__ bias, float* __restrict__ C,
                        float2* __restrict__ psum) {
  int bx = blockIdx.x;
  int wg = (bx & 7) * 500 + (bx >> 3);  // XCD-contiguous
  int mt = wg & 15, nt = wg >> 4;
  int m0 = mt << 7, n0 = nt << 7;

  __shared__ __attribute__((aligned(16))) u16 lds[2 * 4096];  // 16 KB
  __shared__ float2 lsep[128][2];
  char* L = (char*)lds;
  const int tid = threadIdx.x;
  const int lane = tid & 63, wid = tid >> 6;
  const int wm = wid & 1, wn = wid >> 1;
  const int l15 = lane & 15, kq = lane >> 4;

  const int r8 = lane >> 2, ss = lane & 3;
  const int rA0 = (wid << 4) + r8, rA1 = rA0 + 64;
  const u16* gA0 = A + (long)(m0 + rA0) * 1024 + ((ss ^ (rA0 & 3)) << 3);
  const u16* gA1 = A + (long)(m0 + rA1) * 1024 + ((ss ^ (rA1 & 3)) << 3);
  const u16* gB0 = Bw + (long)(n0 + rA0) * 1024 + ((ss ^ (rA0 & 3)) << 3);
  const u16* gB1 = Bw + (long)(n0 + rA1) * 1024 + ((ss ^ (rA1 & 3)) << 3);
  u16* lA0 = (u16*)(L + (wid << 10));
  u16* lA1 = (u16*)(L + 4096 + (wid << 10));
  u16* lB0 = (u16*)(L + 8192 + (wid << 10));
  u16* lB1 = (u16*)(L + 12288 + (wid << 10));

  f32x4 acc[4][4];
  const f32x4 z4 = {0.f, 0.f, 0.f, 0.f};
#pragma unroll
  for (int i = 0; i < 4; ++i)
#pragma unroll
    for (int j = 0; j < 4; ++j) acc[i][j] = z4;

  for (int kt = 0; kt < 32; ++kt) {
    __syncthreads();
    gll16(gA0 + (kt << 5), lA0);
    gll16(gA1 + (kt << 5), lA1);
    gll16(gB0 + (kt << 5), lB0);
    gll16(gB1 + (kt << 5), lB1);
    __syncthreads();
    bf16x8 aF[4], bF[4];
#pragma unroll
    for (int mi = 0; mi < 4; ++mi) {
      int r = (wm << 6) + (mi << 4) + l15;
      aF[mi] = *(const bf16x8*)(L + r * 64 + ((kq ^ (r & 3)) << 4));
    }
#pragma unroll
    for (int ni = 0; ni < 4; ++ni) {
      int c = (wn << 6) + (ni << 4) + l15;
      bF[ni] = *(const bf16x8*)(L + 8192 + c * 64 + ((kq ^ (c & 3)) << 4));
    }
#pragma unroll
    for (int mi = 0; mi < 4; ++mi)
#pragma unroll
      for (int ni = 0; ni < 4; ++ni)
        acc[mi][ni] = __builtin_amdgcn_mfma_f32_16x16x32_bf16(aF[mi], bF[ni], acc[mi][ni], 0, 0, 0);
  }
  // epilogue: bias + scatter + per-row partial LSE
  float b4[4];
#pragma unroll
  for (int ni = 0; ni < 4; ++ni) b4[ni] = bias[n0 + (wn << 6) + (ni << 4) + l15];
#pragma unroll
  for (int mi = 0; mi < 4; ++mi)
#pragma unroll
    for (int e = 0; e < 4; ++e) {
      int r = (wm << 6) + (mi << 4) + (kq << 2) + e;
      int gm = m0 + r;
      float vv[4], vm = -3.0e38f, vs = 0.f;
#pragma unroll
      for (int ni = 0; ni < 4; ++ni) {
        vv[ni] = acc[mi][ni][e] + b4[ni];
        vm = fmaxf(vm, vv[ni]);
      }
#pragma unroll
      for (int ni = 0; ni < 4; ++ni) {
        vs += __expf(vv[ni] - vm);
        int gn = n0 + (wn << 6) + (ni << 4) + l15;
        C[((long)(gm & 63) * T_ + (gm >> 6)) * V_ + gn] = vv[ni];
      }
#pragma unroll
      for (int o = 1; o < 16; o <<= 1) {
        float mo = __shfl_xor(vm, o), so = __shfl_xor(vs, o);
        lse_comb(vm, vs, mo, so);
      }
      if (l15 == 0) lsep[r][wn] = make_float2(vm, vs);
    }
  __syncthreads();
  if (tid < 128) {
    float2 a = lsep[tid][0], b2 = lsep[tid][1];
    float M = a.x, S = a.y;
    lse_comb(M, S, b2.x, b2.y);
    psum[((long)(m0 + tid) << 8) + nt] = make_float2(M, S);
  }
}

// ---------------- grid barrier (R7 verbatim) ----------------
__device__ __forceinline__ void gridbar(unsigned* flags, unsigned seq) {
  __syncthreads();
  if (threadIdx.x == 0)
    __hip_atomic_store(flags + blockIdx.x * 16, seq, __ATOMIC_RELEASE,
                       __HIP_MEMORY_SCOPE_AGENT);
  if (threadIdx.x < 64) {
    int l = threadIdx.x;
    for (;;) {
      unsigned a = __hip_atomic_load(flags + l * 16, __ATOMIC_RELAXED, __HIP_MEMORY_SCOPE_AGENT);
      unsigned b = __hip_atomic_load(flags + (l + 64) * 16, __ATOMIC_RELAXED, __HIP_MEMORY_SCOPE_AGENT);
      unsigned c = __hip_atomic_load(flags + (l + 128) * 16, __ATOMIC_RELAXED, __HIP_MEMORY_SCOPE_AGENT);
      unsigned d = __hip_atomic_load(flags + (l + 192) * 16, __ATOMIC_RELAXED, __HIP_MEMORY_SCOPE_AGENT);
      if (__all((a >= seq) & (b >= seq) & (c >= seq) & (d >= seq))) break;
      __builtin_amdgcn_s_sleep(1);
    }
  }
  __syncthreads();
}

// ---------------- persistent recurrence kernel (R7 verbatim) ----------------
__launch_bounds__(256)
__global__ void k_rec(const float* __restrict__ embi,
                      u16* __restrict__ dctx_h, u16* __restrict__ dctx_l,
                      u16* __restrict__ hh_r, u16* __restrict__ hl_r,
                      const float* __restrict__ memory,
                      const u16* __restrict__ wih_h, const u16* __restrict__ wih_l,
                      const u16* __restrict__ whh_h, const u16* __restrict__ whh_l,
                      const u16* __restrict__ l2_h, const u16* __restrict__ l2_l,
                      float* __restrict__ gip, float* __restrict__ ghp,
                      float* __restrict__ psc, float* __restrict__ ctxp,
                      const float* __restrict__ encT, const float* __restrict__ encL,
                      const int* __restrict__ xs_len,
                      const float* __restrict__ bih, const float* __restrict__ bhh,
                      float* __restrict__ dout, unsigned* flags) {
  extern __shared__ __attribute__((aligned(16))) char L[];
  char* W_HI = L;
  char* W_LO = L + 65536;
  char* A_HI = L + 131072;
  char* A_LO = L + 139264;
  float* hq = (float*)(L + 147456);
  float* at_s = (float*)(L + 148480);
  const int bx = blockIdx.x;
  const int tid = threadIdx.x;
  const int lane = tid & 63, wid = tid >> 6;
  const int wm = wid & 1, wn = wid >> 1;
  const int l15 = lane & 15, kq = lane >> 4;
  const f32x4 z4 = {0.f, 0.f, 0.f, 0.f};
  unsigned seq = 1;

  const int isGI = (bx < 96);
  const int isGH = (bx >= 96 && bx < 192);
  const int isL2 = (bx >= 192 && bx < 224);
  const int sb = bx >> 2;
  const int sq = bx & 3;
  int nt = 0, kc = 0, n0 = 0;
  const u16 *Wg_h = nullptr, *Wg_l = nullptr;
  int wrs = 0;
  if (isGI) {
    nt = bx % 48; kc = bx / 48;
    Wg_h = wih_h + 1024 + (long)nt * 64 * 2048 + kc * 512;
    Wg_l = wih_l + 1024 + (long)nt * 64 * 2048 + kc * 512;
    wrs = 2048;
  } else if (isGH) {
    int j2 = bx - 96;
    nt = j2 % 48; kc = j2 / 48;
    Wg_h = whh_h + (long)nt * 64 * 1024 + kc * 512;
    Wg_l = whh_l + (long)nt * 64 * 1024 + kc * 512;
    wrs = 1024;
  } else if (isL2) {
    n0 = (bx - 192) << 5;
    Wg_h = l2_h + 1024 + (long)n0 * 2048;
    Wg_l = l2_l + 1024 + (long)n0 * 2048;
    wrs = 2048;
  }

  if (isGI || isGH) {
    for (int e = tid; e < 4096; e += 256) {
      int st = e >> 8, r = (e >> 2) & 63, slot = e & 3;
      long g = (long)r * wrs + st * 32 + slot * 8;
      int o = st * 4096 + r * 64 + ((slot ^ (r & 3)) << 4);
      *(u32x4*)(W_HI + o) = *(const u32x4*)(Wg_h + g);
      *(u32x4*)(W_LO + o) = *(const u32x4*)(Wg_l + g);
    }
  } else if (isL2) {
    for (int e = tid; e < 4096; e += 256) {
      int st = e >> 7, r = (e >> 2) & 31, slot = e & 3;
      long g = (long)r * wrs + st * 32 + slot * 8;
      int o = st * 2048 + r * 64 + ((slot ^ (r & 3)) << 4);
      *(u32x4*)(W_HI + o) = *(const u32x4*)(Wg_h + g);
      *(u32x4*)(W_LO + o) = *(const u32x4*)(Wg_l + g);
    }
  }
  __syncthreads();

  float hpv = memory[sb * 1024 + sq * 256 + tid];

  const int pr = tid >> 2, ps = tid & 3;
  const int ao = pr * 64 + ((ps ^ (pr & 3)) << 4);

  for (int t = 0; t < T_; ++t) {
    if (isGI || isGH) {
      const u16* Ah;
      const u16* Al;
      float* outp;
      if (isGI) {
        Ah = dctx_h + (long)t * 65536 + kc * 512;
        Al = dctx_l + (long)t * 65536 + kc * 512;
        outp = gip + (long)kc * 196608 + nt * 64;
      } else {
        Ah = hh_r + (long)t * 65536 + kc * 512;
        Al = hl_r + (long)t * 65536 + kc * 512;
        outp = ghp + (long)kc * 196608 + nt * 64;
      }
      const long g0 = (long)pr * 1024 + ps * 8;
      u32x4 ph0 = *(const u32x4*)(Ah + g0);
      u32x4 ph1 = *(const u32x4*)(Ah + g0 + 32);
      u32x4 pl0 = *(const u32x4*)(Al + g0);
      u32x4 pl1 = *(const u32x4*)(Al + g0 + 32);

      f32x4 acc[2][2];
#pragma unroll
      for (int i = 0; i < 2; ++i)
#pragma unroll
        for (int j = 0; j < 2; ++j) acc[i][j] = z4;

      for (int kt = 0; kt < 8; ++kt) {
        __syncthreads();
        *(u32x4*)(A_HI + ao) = ph0;
        *(u32x4*)(A_HI + 4096 + ao) = ph1;
        *(u32x4*)(A_LO + ao) = pl0;
        *(u32x4*)(A_LO + 4096 + ao) = pl1;
        __syncthreads();
        if (kt < 7) {
          long g = g0 + (kt + 1) * 64;
          ph0 = *(const u32x4*)(Ah + g);
          ph1 = *(const u32x4*)(Ah + g + 32);
          pl0 = *(const u32x4*)(Al + g);
          pl1 = *(const u32x4*)(Al + g + 32);
        }
#pragma unroll
        for (int sub = 0; sub < 2; ++sub) {
          const int stw = (kt * 2 + sub) * 4096;
          const int sta = sub * 4096;
          bf16x8 aH[2], aL[2], bH[2], bL[2];
#pragma unroll
          for (int mi = 0; mi < 2; ++mi) {
            int rr = (wm << 5) + (mi << 4) + l15;
            int off = rr * 64 + ((kq ^ (rr & 3)) << 4);
            aH[mi] = *(const bf16x8*)(A_HI + sta + off);
            aL[mi] = *(const bf16x8*)(A_LO + sta + off);
          }
#pragma unroll
          for (int ni = 0; ni < 2; ++ni) {
            int c = (wn << 5) + (ni << 4) + l15;
            int off = c * 64 + ((kq ^ (c & 3)) << 4);
            bH[ni] = *(const bf16x8*)(W_HI + stw + off);
            bL[ni] = *(const bf16x8*)(W_LO + stw + off);
          }
#pragma unroll
          for (int mi = 0; mi < 2; ++mi)
#pragma unroll
            for (int ni = 0; ni < 2; ++ni) {
              acc[mi][ni] = __builtin_amdgcn_mfma_f32_16x16x32_bf16(aH[mi], bH[ni], acc[mi][ni], 0, 0, 0);
              acc[mi][ni] = __builtin_amdgcn_mfma_f32_16x16x32_bf16(aL[mi], bH[ni], acc[mi][ni], 0, 0, 0);
              acc[mi][ni] = __builtin_amdgcn_mfma_f32_16x16x32_bf16(aH[mi], bL[ni], acc[mi][ni], 0, 0, 0);
            }
        }
      }
#pragma unroll
      for (int mi = 0; mi < 2; ++mi)
#pragma unroll
        for (int ni = 0; ni < 2; ++ni)
#pragma unroll
          for (int e = 0; e < 4; ++e) {
            int r = (wm << 5) + (mi << 4) + (kq << 2) + e;
            int c = (wn << 5) + (ni << 4) + l15;
            astore_f32(outp + (long)r * 3072 + c, acc[mi][ni][e]);
          }
    }
    gridbar(flags, seq); seq++;

    {
      const int b = sb, q = sq;
      const int j = (q << 8) + tid;
      const float* eb = embi + ((long)t * 64 + b) * 3072;
      float g0r = __uint_as_float(aload_u32(gip + b * 3072 + j));
      float g1r = __uint_as_float(aload_u32(gip + 196608 + b * 3072 + j));
      float g0z = __uint_as_float(aload_u32(gip + b * 3072 + 1024 + j));
      float g1z = __uint_as_float(aload_u32(gip + 196608 + b * 3072 + 1024 + j));
      float g0n = __uint_as_float(aload_u32(gip + b * 3072 + 2048 + j));
      float g1n = __uint_as_float(aload_u32(gip + 196608 + b * 3072 + 2048 + j));
      float h0r = __uint_as_float(aload_u32(ghp + b * 3072 + j));
      float h1r = __uint_as_float(aload_u32(ghp + 196608 + b * 3072 + j));
      float h0z = __uint_as_float(aload_u32(ghp + b * 3072 + 1024 + j));
      float h1z = __uint_as_float(aload_u32(ghp + 196608 + b * 3072 + 1024 + j));
      float h0n = __uint_as_float(aload_u32(ghp + b * 3072 + 2048 + j));
      float h1n = __uint_as_float(aload_u32(ghp + 196608 + b * 3072 + 2048 + j));
      float ir = eb[j] + g0r + g1r + bih[j];
      float iz = eb[1024 + j] + g0z + g1z + bih[1024 + j];
      float in2 = eb[2048 + j] + g0n + g1n + bih[2048 + j];
      float hr = h0r + h1r + bhh[j];
      float hz = h0z + h1z + bhh[1024 + j];
      float hn = h0n + h1n + bhh[2048 + j];
      float r = 1.f / (1.f + expf(-(ir + hr)));
      float z = 1.f / (1.f + expf(-(iz + hz)));
      float n = tanhf(in2 + r * hn);
      float h = (1.f - z) * n + z * hpv;
      hpv = h;
      hq[tid] = h;
      if (t == T_ - 1) dout[HID_OFF + (long)b * 1024 + j] = h;
      __syncthreads();
      if (tid < 64) {
        u64 ph = 0, pl = 0;
#pragma unroll
        for (int ii = 0; ii < 4; ++ii) {
          u16 hi, lo;
          split2(hq[tid * 4 + ii], &hi, &lo);
          ph |= (u64)hi << (16 * ii);
          pl |= (u64)lo << (16 * ii);
        }
        long o = (long)(t + 1) * 65536 + (long)b * 1024 + (q << 8) + tid * 4;
        astore_u64(hh_r + o, ph);
        astore_u64(hl_r + o, pl);
      }
      {
        int s = tid >> 2, part = tid & 3;
        const float4* ep = (const float4*)(encT + (((long)b * 64 + s) << 10) + (q << 8) + (part << 6));
        const float4* hp = (const float4*)(hq + (part << 6));
        float dot = 0.f;
#pragma unroll
        for (int kk = 0; kk < 16; ++kk) {
          float4 e = ep[kk], a = hp[kk];
          dot += e.x * a.x + e.y * a.y + e.z * a.z + e.w * a.w;
        }
        dot += __shfl_xor(dot, 1);
        dot += __shfl_xor(dot, 2);
        if (part == 0) astore_f32(psc + (((b << 2) + q) << 6) + s, dot);
      }
    }
    gridbar(flags, seq); seq++;

    {
      const int b = sb, q = sq;
      if (tid < 64) {
        int s = tid;
        float v = 0.f;
#pragma unroll
        for (int qq = 0; qq < 4; ++qq)
          v += __uint_as_float(aload_u32(psc + (((b << 2) + qq) << 6) + s));
        int len = xs_len[b];
        if (s >= len || v == 0.0f) v = -1e10f;
        float m = v;
#pragma unroll
        for (int off = 32; off; off >>= 1) m = fmaxf(m, __shfl_xor(m, off));
        float p = expf(v - m);
        float sum = p;
#pragma unroll
        for (int off = 32; off; off >>= 1) sum += __shfl_xor(sum, off);
        float a = p / sum;
        at_s[s] = a;
        if (q == 0) dout[ATT_OFF + ((long)b * T_ + t) * S_ + s] = a;
      }
      __syncthreads();
      {
        const float* lp = encL + (((long)b * 64 + (q << 4)) << 10) + tid * 4;
        float c0 = 0.f, c1 = 0.f, c2 = 0.f, c3 = 0.f;
#pragma unroll
        for (int s2 = 0; s2 < 16; ++s2) {
          float a = at_s[(q << 4) + s2];
          float4 e = *(const float4*)(lp + (s2 << 10));
          c0 += a * e.x; c1 += a * e.y; c2 += a * e.z; c3 += a * e.w;
        }
        u64 w0 = ((u64)__float_as_uint(c1) << 32) | __float_as_uint(c0);
        u64 w1 = ((u64)__float_as_uint(c3) << 32) | __float_as_uint(c2);
        long o = (((long)(b << 2) + q) << 10) + tid * 4;
        astore_u64(ctxp + o, w0);
        astore_u64(ctxp + o + 2, w1);
      }
    }
    gridbar(flags, seq); seq++;

    if (isL2) {
      const u16* Ah = hh_r + (long)(t + 1) * 65536;
      const u16* Al = hl_r + (long)(t + 1) * 65536;
      const long g0 = (long)pr * 1024 + ps * 8;
      u32x4 ph0 = *(const u32x4*)(Ah + g0);
      u32x4 ph1 = *(const u32x4*)(Ah + g0 + 32);
      u32x4 pl0 = *(const u32x4*)(Al + g0);
      u32x4 pl1 = *(const u32x4*)(Al + g0 + 32);

      f32x4 acc[2];
      acc[0] = z4; acc[1] = z4;
      for (int kt = 0; kt < 16; ++kt) {
        __syncthreads();
        *(u32x4*)(A_HI + ao) = ph0;
        *(u32x4*)(A_HI + 4096 + ao) = ph1;
        *(u32x4*)(A_LO + ao) = pl0;
        *(u32x4*)(A_LO + 4096 + ao) = pl1;
        __syncthreads();
        if (kt < 15) {
          long g = g0 + (kt + 1) * 64;
          ph0 = *(const u32x4*)(Ah + g);
          ph1 = *(const u32x4*)(Ah + g + 32);
          pl0 = *(const u32x4*)(Al + g);
          pl1 = *(const u32x4*)(Al + g + 32);
        }
#pragma unroll
        for (int sub = 0; sub < 2; ++sub) {
          const int stw = (kt * 2 + sub) * 2048;
          const int sta = sub * 4096;
          bf16x8 aH[2], aL[2], bH, bL;
#pragma unroll
          for (int mi = 0; mi < 2; ++mi) {
            int rr = (wm << 5) + (mi << 4) + l15;
            int off = rr * 64 + ((kq ^ (rr & 3)) << 4);
            aH[mi] = *(const bf16x8*)(A_HI + sta + off);
            aL[mi] = *(const bf16x8*)(A_LO + sta + off);
          }
          {
            int c = (wn << 4) + l15;
            int off = c * 64 + ((kq ^ (c & 3)) << 4);
            bH = *(const bf16x8*)(W_HI + stw + off);
            bL = *(const bf16x8*)(W_LO + stw + off);
          }
#pragma unroll
          for (int mi = 0; mi < 2; ++mi) {
            acc[mi] = __builtin_amdgcn_mfma_f32_16x16x32_bf16(aH[mi], bH, acc[mi], 0, 0, 0);
            acc[mi] = __builtin_amdgcn_mfma_f32_16x16x32_bf16(aL[mi], bH, acc[mi], 0, 0, 0);
            acc[mi] = __builtin_amdgcn_mfma_f32_16x16x32_bf16(aH[mi], bL, acc[mi], 0, 0, 0);
          }
        }
      }
      __syncthreads();
      float* cf = (float*)(L + 131072);
#pragma unroll
      for (int mi = 0; mi < 2; ++mi)
#pragma unroll
        for (int e = 0; e < 4; ++e) {
          int rr = (wm << 5) + (mi << 4) + (kq << 2) + e;
          int cc = (wn << 4) + l15;
          float a = 0.f;
#pragma unroll
          for (int qq = 0; qq < 4; ++qq)
            a += __uint_as_float(aload_u32(ctxp + (((long)(rr << 2) + qq) << 10) + n0 + cc));
          float v = tanhf(acc[mi][e] + a);
          if (t == T_ - 1) dout[CTF_OFF + (long)rr * 1024 + n0 + cc] = v;
          cf[rr * 32 + cc] = v;
        }
      __syncthreads();
#pragma unroll
      for (int qq2 = 0; qq2 < 2; ++qq2) {
        int g = tid + qq2 * 256;
        int b = g >> 3, colg = g & 7;
        u64 ph = 0, pl = 0;
#pragma unroll
        for (int ii = 0; ii < 4; ++ii) {
          float v = cf[b * 32 + colg * 4 + ii];
          u16 hi, lo;
          split2(v, &hi, &lo);
          ph |= (u64)hi << (16 * ii);
          pl |= (u64)lo << (16 * ii);
        }
        long o = (long)(t + 1) * 65536 + (long)b * 1024 + n0 + colg * 4;
        astore_u64(dctx_h + o, ph);
        astore_u64(dctx_l + o, pl);
      }
    }
    if (t < T_ - 1) { gridbar(flags, seq); }
    seq++;
  }
}

// ---------------- log-softmax: combine partials + subtract pass ----------------
__launch_bounds__(256)
__global__ void k_lsm(float* __restrict__ dout, const float2* __restrict__ psum) {
  int R = blockIdx.x;  // output row = b*T + t
  long base = (long)R * V_;
  int gm = ((R & 31) << 6) + (R >> 5);
  const float2* pp = psum + ((long)gm << 8);
  int tid = threadIdx.x;
  float m = -3.0e38f, s = 0.f;
  if (tid < 250) {
    float2 p = pp[tid];
    m = p.x;
    s = p.y;
  }
#pragma unroll
  for (int off = 32; off; off >>= 1) {
    float mo = __shfl_xor(m, off), so = __shfl_xor(s, off);
    lse_comb(m, s, mo, so);
  }
  __shared__ float ms[4], ss[4];
  if ((tid & 63) == 0) { ms[tid >> 6] = m; ss[tid >> 6] = s; }
  __syncthreads();
  float M = ms[0], S = ss[0];
  for (int w2 = 1; w2 < 4; ++w2) lse_comb(M, S, ms[w2], ss[w2]);
  float logden = M + logf(S);
  float4* q4 = (float4*)(dout + base);
#pragma unroll 4
  for (int it = 0; it < 31; ++it) {
    float4 x = q4[it * 256 + tid];
    x.x -= logden; x.y -= logden; x.z -= logden; x.w -= logden;
    q4[it * 256 + tid] = x;
  }
  if (tid < 64) {
    float4 x = q4[7936 + tid];
    x.x -= logden; x.y -= logden; x.z -= logden; x.w -= logden;
    q4[7936 + tid] = x;
  }
}

// ---------------- host launcher ----------------
extern "C" void kernel_launch(void* const* d_in, const int* in_sizes, int n_in,
                              void* d_out, int out_size, void* d_ws, size_t ws_size,
                              hipStream_t stream) {
  (void)in_sizes; (void)n_in; (void)out_size;
  const int* input = (const int*)d_in[0];
  const float* memory = (const float*)d_in[1];
  const float* enc = (const float*)d_in[2];
  const int* xs_len = (const int*)d_in[3];
  const float* emb = (const float*)d_in[4];
  const float* wih = (const float*)d_in[5];
  const float* whh = (const float*)d_in[6];
  const float* bih = (const float*)d_in[7];
  const float* bhh = (const float*)d_in[8];
  const float* l1 = (const float*)d_in[9];
  const float* l2 = (const float*)d_in[10];
  const float* wout = (const float*)d_in[11];
  const float* bout = (const float*)d_in[12];
  float* out = (float*)d_out;
  char* w = (char*)d_ws;

  size_t off = 0;
  auto alloc = [&](size_t bytes) {
    size_t o = off;
    off = (off + bytes + 255) & ~(size_t)255;
    return o;
  };
  const size_t N_WIH = 3072UL * 2048, N_WHH = 3072UL * 1024, N_L2 = 1024UL * 2048;
  const size_t N_L1 = 1024UL * 1024, N_ENC = 4096UL * 1024, N_WOUT = 32000UL * 1024;
  const size_t N_EMBX = 2048UL * 1024, N_ENCT = 4096UL * 1024;
  const size_t N_EMBI = 2048UL * 3072, N_ROT = 33UL * 65536;

  size_t o_wih_h = alloc(2 * N_WIH), o_wih_l = alloc(2 * N_WIH);
  size_t o_whh_h = alloc(2 * N_WHH), o_whh_l = alloc(2 * N_WHH);
  size_t o_l2_h = alloc(2 * N_L2), o_l2_l = alloc(2 * N_L2);
  size_t o_l1t_h = alloc(2 * N_L1), o_l1t_l = alloc(2 * N_L1);
  size_t o_ctx_h = alloc(2 * N_ROT), o_ctx_l = alloc(2 * N_ROT);
  size_t o_hh = alloc(2 * N_ROT), o_hl = alloc(2 * N_ROT);
  size_t o_gip = alloc(4 * 2 * 196608), o_ghp = alloc(4 * 2 * 196608);
  size_t o_psc = alloc(4 * 16384);
  size_t o_ctxp = alloc(4 * 262144);
  size_t o_psum = alloc(8UL * 2048 * 256);
  size_t o_bar = alloc(16384);
  size_t o_arena = alloc(2 * N_ENC * 2 + 2 * N_EMBX * 2 + 4 * N_EMBI + 4 * N_ENCT * 2);

  if (off > ws_size) {
    k_guard<<<1, 1, 0, stream>>>(out, 1.0e8f + (float)(ws_size >> 20));
    return;
  }

  u16* wih_h = (u16*)(w + o_wih_h);   u16* wih_l = (u16*)(w + o_wih_l);
  u16* whh_h = (u16*)(w + o_whh_h);   u16* whh_l = (u16*)(w + o_whh_l);
  u16* l2_h = (u16*)(w + o_l2_h);     u16* l2_l = (u16*)(w + o_l2_l);
  u16* l1t_h = (u16*)(w + o_l1t_h);   u16* l1t_l = (u16*)(w + o_l1t_l);
  u16* ctx_h = (u16*)(w + o_ctx_h);   u16* ctx_l = (u16*)(w + o_ctx_l);
  u16* hh_r = (u16*)(w + o_hh);       u16* hl_r = (u16*)(w + o_hl);
  float* gip = (float*)(w + o_gip);
  float* ghp = (float*)(w + o_ghp);
  float* psc = (float*)(w + o_psc);
  float* ctxp = (float*)(w + o_ctxp);
  float2* psum = (float2*)(w + o_psum);
  unsigned* flags = (unsigned*)(w + o_bar);

  char* ar = w + o_arena;
  u16* enc_h = (u16*)ar;
  u16* enc_l = (u16*)(ar + 2 * N_ENC);
  u16* embx_h = (u16*)(ar + 4 * N_ENC);
  u16* embx_l = (u16*)(ar + 4 * N_ENC + 2 * N_EMBX);
  float* embi = (float*)(ar + 4 * N_ENC + 4 * N_EMBX);
  float* encT = (float*)(ar + 4 * N_ENC + 4 * N_EMBX + 4 * N_EMBI);
  float* encL = (float*)(ar + 4 * N_ENC + 4 * N_EMBX + 4 * N_EMBI + 4 * N_ENCT);
  u16* wout_b = (u16*)ar;  // overlays prep arena after k_rec

  hipFuncSetAttribute((const void*)k_rec, hipFuncAttributeMaxDynamicSharedMemorySize,
                      LDS_BYTES);

  // prep (fused splits)
  k_split4<<<4096, 256, 0, stream>>>(wih, wih_h, wih_l, (int)N_WIH,
                                     whh, whh_h, whh_l, (int)N_WHH,
                                     l2, l2_h, l2_l, (int)N_L2,
                                     enc, enc_h, enc_l, (int)N_ENC);
  k_l1t<<<256, 256, 0, stream>>>(l1, l1t_h, l1t_l);
  k_embx<<<2048, 256, 0, stream>>>(input, emb, embx_h, embx_l);
  k_h0<<<256, 256, 0, stream>>>(memory, hh_r, hl_r);
  hipMemsetAsync(ctx_h, 0, 131072, stream);
  hipMemsetAsync(ctx_l, 0, 131072, stream);
  hipMemsetAsync(flags, 0, 16384, stream);

  // encT = enc @ l1 ; encL = enc @ l2a^T ; embi = embx @ w_ih[:, :1024]^T
  k_gemmG<<<256, 256, 0, stream>>>(enc_h, enc_l, l1t_h, l1t_l, encT,
                                   32, 1024, 1024, 1024);
  k_gemmG<<<256, 256, 0, stream>>>(enc_h, enc_l, l2_h, l2_l, encL,
                                   32, 1024, 2048, 1024);
  k_gemmG<<<384, 256, 0, stream>>>(embx_h, embx_l, wih_h, wih_l, embi,
                                   16, 1024, 2048, 3072);

  // persistent recurrence (R7 verbatim)
  k_rec<<<NB_, 256, LDS_BYTES, stream>>>(embi, ctx_h, ctx_l, hh_r, hl_r, memory,
                                         wih_h, wih_l, whh_h, whh_l, l2_h, l2_l,
                                         gip, ghp, psc, ctxp, encT, encL,
                                         xs_len, bih, bhh, out, flags);

  // wout -> bf16 (overlays dead prep arena)
  k_tobf<<<4096, 256, 0, stream>>>(wout, wout_b, (int)N_WOUT);

  // logits GEMM (gll16 staging, XCD-contiguous nt) + partial LSE
  k_gemmL<<<4000, 256, 0, stream>>>(ctx_h + 65536, wout_b, bout, out, psum);

  // log-softmax: combine partials, subtract in place
  k_lsm<<<2048, 256, 0, stream>>>(out, psum);
}